// Round 4
// baseline (763.975 us; speedup 1.0000x reference)
//
#include <hip/hip_runtime.h>
#include <hip/hip_bf16.h>

// GAT (3 layers) + MLP head. N=50000, E=800000 (+N self loops), D=128, H=256, C=6.
// Round 4: GEMM restructured — B panel (K=128 x BN) staged once in LDS, A streamed
// from global into registers (2-group pipeline). Removes A's LDS round-trip, which
// was the LDS-throughput bottleneck (3 b128/kk -> 1 b128/kk per wave).
// Plus: 3-kernel parallel CSR scan, aggregate 4x unroll, merged memsets.

#define BM 128
#define BN 64
// K is fixed at 128 for every GEMM in this model.

__global__ __launch_bounds__(256) void k_hist(const int* __restrict__ ei, int* __restrict__ deg,
                                              int E_, int N_) {
    int e = blockIdx.x * 256 + threadIdx.x;
    int total = E_ + N_;
    if (e >= total) return;
    int d = (e < E_) ? ei[E_ + e] : (e - E_);
    atomicAdd(&deg[d], 1);
}

// block-level exclusive scan helper pieces (256 threads)
__device__ inline int block_incl_scan(int v, int* wsum) {
    int lane = threadIdx.x & 63, wid = threadIdx.x >> 6;
    #pragma unroll
    for (int d = 1; d < 64; d <<= 1) {
        int t = __shfl_up(v, d);
        if (lane >= d) v += t;
    }
    if (lane == 63) wsum[wid] = v;
    __syncthreads();
    if (wid == 0 && lane < 4) {
        int s = wsum[lane];
        #pragma unroll
        for (int d = 1; d < 4; d <<= 1) {
            int t = __shfl_up(s, d);
            if (lane >= d) s += t;
        }
        wsum[lane] = s;
    }
    __syncthreads();
    if (wid > 0) v += wsum[wid - 1];
    return v;
}

__global__ __launch_bounds__(256) void k_bsum(const int* __restrict__ deg, int* __restrict__ bsum, int n) {
    __shared__ int wsum[4];
    int i = blockIdx.x * 256 + threadIdx.x;
    int v = (i < n) ? deg[i] : 0;
    int lane = threadIdx.x & 63, wid = threadIdx.x >> 6;
    #pragma unroll
    for (int d = 32; d > 0; d >>= 1) v += __shfl_down(v, d);
    if (lane == 0) wsum[wid] = v;
    __syncthreads();
    if (threadIdx.x == 0) bsum[blockIdx.x] = wsum[0] + wsum[1] + wsum[2] + wsum[3];
}

// single block: exclusive scan of bsum[0..nb) in place
__global__ __launch_bounds__(256) void k_scanb(int* __restrict__ bsum, int nb) {
    __shared__ int wsum[4];
    int i = threadIdx.x;
    int orig = (i < nb) ? bsum[i] : 0;
    int v = block_incl_scan(orig, wsum);
    if (i < nb) bsum[i] = v - orig;
}

__global__ __launch_bounds__(256) void k_off(const int* __restrict__ deg, const int* __restrict__ bsum,
                                             int* __restrict__ off, int n) {
    __shared__ int wsum[4];
    int i = blockIdx.x * 256 + threadIdx.x;
    int orig = (i < n) ? deg[i] : 0;
    int v = block_incl_scan(orig, wsum);
    int base = bsum[blockIdx.x];
    if (i < n) off[i] = base + v - orig;
    if (i == n - 1) off[n] = base + v;
}

__global__ __launch_bounds__(256) void k_scatter(const int* __restrict__ ei, const int* __restrict__ off,
                                                 int* __restrict__ cur, int* __restrict__ csrc,
                                                 int E_, int N_) {
    int e = blockIdx.x * 256 + threadIdx.x;
    int total = E_ + N_;
    if (e >= total) return;
    int s, d;
    if (e < E_) { s = ei[e]; d = ei[E_ + e]; }
    else        { s = e - E_; d = e - E_; }
    int pos = off[d] + atomicAdd(&cur[d], 1);
    csrc[pos] = s;
}

// C[M x Ncol] = A[M x 128] @ B[128 x Ncol] (+bias)(relu).
// B column-panel (128 x 64) staged once in LDS; A streamed global->regs, 2-group pipeline.
// Thread (g,c): rows {bm+g*4..+3, bm+64+g*4..+3}, cols bn+c*4..+3.
__global__ __launch_bounds__(256) void k_gemm(const float* __restrict__ A, const float* __restrict__ B,
                                              const float* __restrict__ bias, float* __restrict__ C,
                                              int M, int Ncol, int has_bias, int relu) {
    __shared__ float Bs[128][BN];   // 32 KB, row stride 64 -> 2-way bank aliasing (free)
    int bm = blockIdx.y * BM;
    int bn = blockIdx.x * BN;
    int tid = threadIdx.x;
    int g = tid >> 4, c = tid & 15;
    int tc = c * 4;
    // stage B panel: 2048 float4, 8 per thread
    #pragma unroll
    for (int i = 0; i < 8; ++i) {
        int idx = i * 256 + tid;
        int br = idx >> 4;
        int bc = (idx & 15) * 4;
        *(float4*)&Bs[br][bc] = *(const float4*)(B + (size_t)br * Ncol + bn + bc);
    }
    __syncthreads();

    const float* ar[8];
    bool inb[8];
    int rr[8];
    #pragma unroll
    for (int r = 0; r < 8; ++r) {
        int row = bm + ((r < 4) ? (g * 4 + r) : (64 + g * 4 + (r - 4)));
        rr[r] = row;
        inb[r] = row < M;
        ar[r] = A + (size_t)(inb[r] ? row : (M - 1)) * 128;
    }
    float acc[8][4] = {};
    float4 a0[8], a1[8];
    #pragma unroll
    for (int r = 0; r < 8; ++r) a0[r] = *(const float4*)(ar[r]);

    #pragma unroll 4
    for (int grp = 0; grp < 32; grp += 2) {
        #pragma unroll
        for (int r = 0; r < 8; ++r) a1[r] = *(const float4*)(ar[r] + (grp + 1) * 4);
        #pragma unroll
        for (int j = 0; j < 4; ++j) {
            float4 b = *(const float4*)&Bs[grp * 4 + j][tc];
            #pragma unroll
            for (int r = 0; r < 8; ++r) {
                float a = (&a0[r].x)[j];
                acc[r][0] += a * b.x;
                acc[r][1] += a * b.y;
                acc[r][2] += a * b.z;
                acc[r][3] += a * b.w;
            }
        }
        if (grp + 2 < 32) {
            #pragma unroll
            for (int r = 0; r < 8; ++r) a0[r] = *(const float4*)(ar[r] + (grp + 2) * 4);
        }
        #pragma unroll
        for (int j = 0; j < 4; ++j) {
            float4 b = *(const float4*)&Bs[(grp + 1) * 4 + j][tc];
            #pragma unroll
            for (int r = 0; r < 8; ++r) {
                float a = (&a1[r].x)[j];
                acc[r][0] += a * b.x;
                acc[r][1] += a * b.y;
                acc[r][2] += a * b.z;
                acc[r][3] += a * b.w;
            }
        }
    }
    float4 bv = make_float4(0.f, 0.f, 0.f, 0.f);
    if (has_bias) bv = *(const float4*)(bias + bn + tc);
    #pragma unroll
    for (int r = 0; r < 8; ++r) {
        if (!inb[r]) continue;
        float4 o;
        o.x = acc[r][0] + bv.x;
        o.y = acc[r][1] + bv.y;
        o.z = acc[r][2] + bv.z;
        o.w = acc[r][3] + bv.w;
        if (relu) {
            o.x = fmaxf(o.x, 0.f); o.y = fmaxf(o.y, 0.f);
            o.z = fmaxf(o.z, 0.f); o.w = fmaxf(o.w, 0.f);
        }
        *(float4*)(C + (size_t)rr[r] * Ncol + bn + tc) = o;
    }
}

// per-node attention coefficients: avs[n] = h[n].asrc, avd[n] = h[n].adst  (D=128)
__global__ __launch_bounds__(256) void k_alpha(const float* __restrict__ h, const float* __restrict__ asrc,
                                               const float* __restrict__ adst, float* __restrict__ avs,
                                               float* __restrict__ avd, int n) {
    int w = (blockIdx.x * 256 + threadIdx.x) >> 6;
    int lane = threadIdx.x & 63;
    if (w >= n) return;
    float2 hv = ((const float2*)(h + (size_t)w * 128))[lane];
    float2 s2 = ((const float2*)asrc)[lane];
    float2 d2 = ((const float2*)adst)[lane];
    float vs = hv.x * s2.x + hv.y * s2.y;
    float vd = hv.x * d2.x + hv.y * d2.y;
    #pragma unroll
    for (int d = 32; d > 0; d >>= 1) {
        vs += __shfl_down(vs, d);
        vd += __shfl_down(vd, d);
    }
    if (lane == 0) { avs[w] = vs; avd[w] = vd; }
}

// one wave per dst node: 2-pass segment softmax + weighted aggregate + bias + relu.
// Pass 2: half-wave (32 lanes) per edge, float4 row loads, 4x unroll (8 edges in flight/wave).
__global__ __launch_bounds__(256) void k_aggregate(const float* __restrict__ h, const int* __restrict__ off,
                                                   const int* __restrict__ csrc, const float* __restrict__ avs,
                                                   const float* __restrict__ avd, const float* __restrict__ bias,
                                                   float* __restrict__ out, int n) {
    int w = (blockIdx.x * 256 + threadIdx.x) >> 6;
    int lane = threadIdx.x & 63;
    if (w >= n) return;
    int half = lane >> 5;
    int sl = lane & 31;
    int beg = off[w], end = off[w + 1];
    float adn = avd[w];
    // pass 1: max score, edge-parallel across all 64 lanes
    float m = -1e30f;
    for (int j = beg + lane; j < end; j += 64) {
        float sc = avs[csrc[j]] + adn;
        sc = (sc < 0.f) ? 0.2f * sc : sc;
        m = fmaxf(m, sc);
    }
    #pragma unroll
    for (int d = 32; d > 0; d >>= 1) m = fmaxf(m, __shfl_xor(m, d));
    // pass 2
    float4 acc = make_float4(0.f, 0.f, 0.f, 0.f);
    float ssum = 0.f;
    int j = beg + half;
    for (; j + 6 < end; j += 8) {
        int s0 = csrc[j], s1 = csrc[j + 2], s2 = csrc[j + 4], s3 = csrc[j + 6];
        float4 h0 = *((const float4*)(h + (size_t)s0 * 128) + sl);
        float4 h1 = *((const float4*)(h + (size_t)s1 * 128) + sl);
        float4 h2 = *((const float4*)(h + (size_t)s2 * 128) + sl);
        float4 h3 = *((const float4*)(h + (size_t)s3 * 128) + sl);
        float sc0 = avs[s0] + adn; sc0 = (sc0 < 0.f) ? 0.2f * sc0 : sc0;
        float sc1 = avs[s1] + adn; sc1 = (sc1 < 0.f) ? 0.2f * sc1 : sc1;
        float sc2 = avs[s2] + adn; sc2 = (sc2 < 0.f) ? 0.2f * sc2 : sc2;
        float sc3 = avs[s3] + adn; sc3 = (sc3 < 0.f) ? 0.2f * sc3 : sc3;
        float e0 = __expf(sc0 - m), e1 = __expf(sc1 - m);
        float e2 = __expf(sc2 - m), e3 = __expf(sc3 - m);
        ssum += (e0 + e1) + (e2 + e3);
        acc.x += e0 * h0.x + e1 * h1.x + e2 * h2.x + e3 * h3.x;
        acc.y += e0 * h0.y + e1 * h1.y + e2 * h2.y + e3 * h3.y;
        acc.z += e0 * h0.z + e1 * h1.z + e2 * h2.z + e3 * h3.z;
        acc.w += e0 * h0.w + e1 * h1.w + e2 * h2.w + e3 * h3.w;
    }
    for (; j < end; j += 2) {
        int s0 = csrc[j];
        float4 h0 = *((const float4*)(h + (size_t)s0 * 128) + sl);
        float sc0 = avs[s0] + adn; sc0 = (sc0 < 0.f) ? 0.2f * sc0 : sc0;
        float e0 = __expf(sc0 - m);
        ssum += e0;
        acc.x += e0 * h0.x;
        acc.y += e0 * h0.y;
        acc.z += e0 * h0.z;
        acc.w += e0 * h0.w;
    }
    ssum  += __shfl_xor(ssum, 32);
    acc.x += __shfl_xor(acc.x, 32);
    acc.y += __shfl_xor(acc.y, 32);
    acc.z += __shfl_xor(acc.z, 32);
    acc.w += __shfl_xor(acc.w, 32);
    if (half == 0) {
        float inv = 1.f / ssum;
        float4 b = ((const float4*)bias)[sl];
        float4 o;
        o.x = fmaxf(acc.x * inv + b.x, 0.f);
        o.y = fmaxf(acc.y * inv + b.y, 0.f);
        o.z = fmaxf(acc.z * inv + b.z, 0.f);
        o.w = fmaxf(acc.w * inv + b.w, 0.f);
        *((float4*)(out + (size_t)w * 128) + sl) = o;
    }
}

// out[n,c] = mid[n,:256] @ Wm2[:,c] + bm2[c]; one wave per node, Wm2 in LDS
__global__ __launch_bounds__(256) void k_mlp2(const float* __restrict__ mid, const float* __restrict__ W2,
                                              const float* __restrict__ b2, float* __restrict__ out, int n) {
    __shared__ float Ws[256 * 6];
    int tid = threadIdx.x;
    for (int t = tid; t < 256 * 6; t += 256) Ws[t] = W2[t];
    __syncthreads();
    int w = (blockIdx.x * 256 + tid) >> 6;
    int lane = tid & 63;
    if (w >= n) return;
    float acc[6];
    float4 mv = ((const float4*)(mid + (size_t)w * 256))[lane];
    int k0 = lane * 4;
    #pragma unroll
    for (int c = 0; c < 6; ++c)
        acc[c] = mv.x * Ws[k0 * 6 + c] + mv.y * Ws[(k0 + 1) * 6 + c]
               + mv.z * Ws[(k0 + 2) * 6 + c] + mv.w * Ws[(k0 + 3) * 6 + c];
    #pragma unroll
    for (int c = 0; c < 6; ++c)
        #pragma unroll
        for (int d = 32; d > 0; d >>= 1) acc[c] += __shfl_down(acc[c], d);
    if (lane == 0) {
        #pragma unroll
        for (int c = 0; c < 6; ++c) out[(size_t)w * 6 + c] = acc[c] + b2[c];
    }
}

extern "C" void kernel_launch(void* const* d_in, const int* in_sizes, int n_in,
                              void* d_out, int out_size, void* d_ws, size_t ws_size,
                              hipStream_t stream) {
    const float* x   = (const float*)d_in[0];
    const int*   ei  = (const int*)d_in[1];
    const float* W[3]    = {(const float*)d_in[2], (const float*)d_in[6], (const float*)d_in[10]};
    const float* bL[3]   = {(const float*)d_in[3], (const float*)d_in[7], (const float*)d_in[11]};
    const float* asr[3]  = {(const float*)d_in[4], (const float*)d_in[8], (const float*)d_in[12]};
    const float* ads[3]  = {(const float*)d_in[5], (const float*)d_in[9], (const float*)d_in[13]};
    const float* Wm1 = (const float*)d_in[14];
    const float* bm1 = (const float*)d_in[15];
    const float* Wm2 = (const float*)d_in[16];
    const float* bm2 = (const float*)d_in[17];
    float* out = (float*)d_out;

    const int N_ = in_sizes[0] / 128;
    const int E_ = in_sizes[1] / 2;
    const int TOT = E_ + N_;
    const int NB = (N_ + 255) / 256;   // scan blocks

    char* p = (char*)d_ws;
    auto alloc = [&](size_t bytes) { void* r = (void*)p; p += (bytes + 255) & ~(size_t)255; return r; };
    size_t npad = ((size_t)N_ * 4 + 255) & ~(size_t)255;
    int*   deg  = (int*)alloc(npad);
    int*   cur  = (int*)alloc(npad);
    int*   off  = (int*)alloc((size_t)(N_ + 1) * 4);
    int*   bsum = (int*)alloc((size_t)(NB + 1) * 4);
    int*   csrc = (int*)alloc((size_t)TOT * 4);
    float* avs  = (float*)alloc((size_t)N_ * 4);
    float* avd  = (float*)alloc((size_t)N_ * 4);
    float* buf1 = (float*)alloc((size_t)N_ * 256 * 4);
    float* buf2 = (float*)alloc((size_t)N_ * 128 * 4);

    // ---- CSR build ----
    hipMemsetAsync(deg, 0, npad * 2, stream);   // zero deg AND cur in one call (contiguous)
    k_hist<<<(TOT + 255) / 256, 256, 0, stream>>>(ei, deg, E_, N_);
    k_bsum<<<NB, 256, 0, stream>>>(deg, bsum, N_);
    k_scanb<<<1, 256, 0, stream>>>(bsum, NB);
    k_off<<<NB, 256, 0, stream>>>(deg, bsum, off, N_);
    k_scatter<<<(TOT + 255) / 256, 256, 0, stream>>>(ei, off, cur, csrc, E_, N_);

    const int wave_blocks = (N_ + 3) / 4;
    dim3 gemm_grid(128 / BN, (N_ + BM - 1) / BM);

    // ---- 3 GAT layers ----
    const float* cur_in = x;
    for (int l = 0; l < 3; ++l) {
        k_gemm<<<gemm_grid, 256, 0, stream>>>(cur_in, W[l], nullptr, buf1, N_, 128, 0, 0);
        k_alpha<<<wave_blocks, 256, 0, stream>>>(buf1, asr[l], ads[l], avs, avd, N_);
        k_aggregate<<<wave_blocks, 256, 0, stream>>>(buf1, off, csrc, avs, avd, bL[l], buf2, N_);
        cur_in = buf2;
    }

    // ---- MLP head ----
    dim3 gm1(256 / BN, (N_ + BM - 1) / BM);
    k_gemm<<<gm1, 256, 0, stream>>>(buf2, Wm1, bm1, buf1, N_, 256, 1, 1);
    k_mlp2<<<wave_blocks, 256, 0, stream>>>(buf1, Wm2, bm2, out, N_);
}

// Round 5
// 558.787 us; speedup vs baseline: 1.3672x; 1.3672x over previous
//
#include <hip/hip_runtime.h>
#include <hip/hip_bf16.h>

// GAT (3 layers) + MLP head. N=50000, E=800000 (+N self loops), D=128, H=256, C=6.
// Round 5: GEMM back to LDS-tiled (R3 structure) but 8x8 per-thread tile
// (BM=BN=128, BK=16): LDS bytes/FMA drops 1.5 -> 1.0, VALU ceiling 44% -> 66%,
// while VGPRs stay ~110 (launch_bounds(256,4) -> 16 waves/CU). R4's A-streaming
// variant died on occupancy (236 VGPR, 9.5% occ). Scan/aggregate kept from R4.

#define BM 128
#define BN 128
#define BK 16
// K is fixed at 128 for every GEMM in this model.

__global__ __launch_bounds__(256) void k_hist(const int* __restrict__ ei, int* __restrict__ deg,
                                              int E_, int N_) {
    int e = blockIdx.x * 256 + threadIdx.x;
    int total = E_ + N_;
    if (e >= total) return;
    int d = (e < E_) ? ei[E_ + e] : (e - E_);
    atomicAdd(&deg[d], 1);
}

// block-level inclusive scan (256 threads)
__device__ inline int block_incl_scan(int v, int* wsum) {
    int lane = threadIdx.x & 63, wid = threadIdx.x >> 6;
    #pragma unroll
    for (int d = 1; d < 64; d <<= 1) {
        int t = __shfl_up(v, d);
        if (lane >= d) v += t;
    }
    if (lane == 63) wsum[wid] = v;
    __syncthreads();
    if (wid == 0 && lane < 4) {
        int s = wsum[lane];
        #pragma unroll
        for (int d = 1; d < 4; d <<= 1) {
            int t = __shfl_up(s, d);
            if (lane >= d) s += t;
        }
        wsum[lane] = s;
    }
    __syncthreads();
    if (wid > 0) v += wsum[wid - 1];
    return v;
}

__global__ __launch_bounds__(256) void k_bsum(const int* __restrict__ deg, int* __restrict__ bsum, int n) {
    __shared__ int wsum[4];
    int i = blockIdx.x * 256 + threadIdx.x;
    int v = (i < n) ? deg[i] : 0;
    int lane = threadIdx.x & 63, wid = threadIdx.x >> 6;
    #pragma unroll
    for (int d = 32; d > 0; d >>= 1) v += __shfl_down(v, d);
    if (lane == 0) wsum[wid] = v;
    __syncthreads();
    if (threadIdx.x == 0) bsum[blockIdx.x] = wsum[0] + wsum[1] + wsum[2] + wsum[3];
}

__global__ __launch_bounds__(256) void k_scanb(int* __restrict__ bsum, int nb) {
    __shared__ int wsum[4];
    int i = threadIdx.x;
    int orig = (i < nb) ? bsum[i] : 0;
    int v = block_incl_scan(orig, wsum);
    if (i < nb) bsum[i] = v - orig;
}

__global__ __launch_bounds__(256) void k_off(const int* __restrict__ deg, const int* __restrict__ bsum,
                                             int* __restrict__ off, int n) {
    __shared__ int wsum[4];
    int i = blockIdx.x * 256 + threadIdx.x;
    int orig = (i < n) ? deg[i] : 0;
    int v = block_incl_scan(orig, wsum);
    int base = bsum[blockIdx.x];
    if (i < n) off[i] = base + v - orig;
    if (i == n - 1) off[n] = base + v;
}

__global__ __launch_bounds__(256) void k_scatter(const int* __restrict__ ei, const int* __restrict__ off,
                                                 int* __restrict__ cur, int* __restrict__ csrc,
                                                 int E_, int N_) {
    int e = blockIdx.x * 256 + threadIdx.x;
    int total = E_ + N_;
    if (e >= total) return;
    int s, d;
    if (e < E_) { s = ei[e]; d = ei[E_ + e]; }
    else        { s = e - E_; d = e - E_; }
    int pos = off[d] + atomicAdd(&cur[d], 1);
    csrc[pos] = s;
}

// C[M x Ncol] = A[M x 128] @ B[128 x Ncol] (+bias)(relu).
// 128x128 tile, 256 threads, 8x8 acc/thread (rows {r0,64+r0}, cols {c0,64+c0}),
// all LDS traffic b128 at <=2-way bank aliasing.
__global__ __launch_bounds__(256, 4) void k_gemm(const float* __restrict__ A, const float* __restrict__ B,
                                                 const float* __restrict__ bias, float* __restrict__ C,
                                                 int M, int Ncol, int has_bias, int relu) {
    __shared__ float As[BK][BM + 4];   // transposed: As[k][m]
    __shared__ float Bs[BK][BN + 4];
    int bm = blockIdx.y * BM;
    int bn = blockIdx.x * BN;
    int tid = threadIdx.x;
    int g = tid >> 4, c = tid & 15;
    int r0 = g * 4, c0 = c * 4;
    float acc[8][8] = {};
    for (int k0 = 0; k0 < 128; k0 += BK) {
        // stage A: 128 rows x 16 cols, 2 float4/thread, store transposed
        #pragma unroll
        for (int i = 0; i < 2; ++i) {
            int idx = i * 256 + tid;          // 0..511
            int row = idx >> 2;               // 0..127
            int j4 = (idx & 3) * 4;           // 0,4,8,12
            int grow = bm + row;
            float4 v = make_float4(0.f, 0.f, 0.f, 0.f);
            if (grow < M) v = *(const float4*)(A + (size_t)grow * 128 + k0 + j4);
            As[j4 + 0][row] = v.x;
            As[j4 + 1][row] = v.y;
            As[j4 + 2][row] = v.z;
            As[j4 + 3][row] = v.w;
        }
        // stage B: 16 rows x 128 cols, 2 float4/thread
        #pragma unroll
        for (int i = 0; i < 2; ++i) {
            int idx = i * 256 + tid;          // 0..511
            int br = idx >> 5;                // 0..15
            int bc = (idx & 31) * 4;          // 0..124
            *(float4*)&Bs[br][bc] = *(const float4*)(B + (size_t)(k0 + br) * Ncol + bn + bc);
        }
        __syncthreads();
        #pragma unroll
        for (int kk = 0; kk < BK; ++kk) {
            float4 a0 = *(const float4*)&As[kk][r0];
            float4 a1 = *(const float4*)&As[kk][64 + r0];
            float4 b0 = *(const float4*)&Bs[kk][c0];
            float4 b1 = *(const float4*)&Bs[kk][64 + c0];
            float av[8] = {a0.x, a0.y, a0.z, a0.w, a1.x, a1.y, a1.z, a1.w};
            float bv[8] = {b0.x, b0.y, b0.z, b0.w, b1.x, b1.y, b1.z, b1.w};
            #pragma unroll
            for (int x = 0; x < 8; ++x)
                #pragma unroll
                for (int y = 0; y < 8; ++y)
                    acc[x][y] += av[x] * bv[y];
        }
        __syncthreads();
    }
    float4 bvl = make_float4(0.f, 0.f, 0.f, 0.f);
    float4 bvh = make_float4(0.f, 0.f, 0.f, 0.f);
    if (has_bias) {
        bvl = *(const float4*)(bias + bn + c0);
        bvh = *(const float4*)(bias + bn + 64 + c0);
    }
    #pragma unroll
    for (int x = 0; x < 8; ++x) {
        int row = bm + ((x < 4) ? (r0 + x) : (64 + r0 + (x - 4)));
        if (row >= M) continue;
        float4 o0, o1;
        o0.x = acc[x][0] + bvl.x; o0.y = acc[x][1] + bvl.y;
        o0.z = acc[x][2] + bvl.z; o0.w = acc[x][3] + bvl.w;
        o1.x = acc[x][4] + bvh.x; o1.y = acc[x][5] + bvh.y;
        o1.z = acc[x][6] + bvh.z; o1.w = acc[x][7] + bvh.w;
        if (relu) {
            o0.x = fmaxf(o0.x, 0.f); o0.y = fmaxf(o0.y, 0.f);
            o0.z = fmaxf(o0.z, 0.f); o0.w = fmaxf(o0.w, 0.f);
            o1.x = fmaxf(o1.x, 0.f); o1.y = fmaxf(o1.y, 0.f);
            o1.z = fmaxf(o1.z, 0.f); o1.w = fmaxf(o1.w, 0.f);
        }
        *(float4*)(C + (size_t)row * Ncol + bn + c0)      = o0;
        *(float4*)(C + (size_t)row * Ncol + bn + 64 + c0) = o1;
    }
}

// per-node attention coefficients: avs[n] = h[n].asrc, avd[n] = h[n].adst  (D=128)
__global__ __launch_bounds__(256) void k_alpha(const float* __restrict__ h, const float* __restrict__ asrc,
                                               const float* __restrict__ adst, float* __restrict__ avs,
                                               float* __restrict__ avd, int n) {
    int w = (blockIdx.x * 256 + threadIdx.x) >> 6;
    int lane = threadIdx.x & 63;
    if (w >= n) return;
    float2 hv = ((const float2*)(h + (size_t)w * 128))[lane];
    float2 s2 = ((const float2*)asrc)[lane];
    float2 d2 = ((const float2*)adst)[lane];
    float vs = hv.x * s2.x + hv.y * s2.y;
    float vd = hv.x * d2.x + hv.y * d2.y;
    #pragma unroll
    for (int d = 32; d > 0; d >>= 1) {
        vs += __shfl_down(vs, d);
        vd += __shfl_down(vd, d);
    }
    if (lane == 0) { avs[w] = vs; avd[w] = vd; }
}

// one wave per dst node: 2-pass segment softmax + weighted aggregate + bias + relu.
// Pass 2: half-wave (32 lanes) per edge, float4 row loads, 4x unroll (8 edges in flight/wave).
__global__ __launch_bounds__(256) void k_aggregate(const float* __restrict__ h, const int* __restrict__ off,
                                                   const int* __restrict__ csrc, const float* __restrict__ avs,
                                                   const float* __restrict__ avd, const float* __restrict__ bias,
                                                   float* __restrict__ out, int n) {
    int w = (blockIdx.x * 256 + threadIdx.x) >> 6;
    int lane = threadIdx.x & 63;
    if (w >= n) return;
    int half = lane >> 5;
    int sl = lane & 31;
    int beg = off[w], end = off[w + 1];
    float adn = avd[w];
    float m = -1e30f;
    for (int j = beg + lane; j < end; j += 64) {
        float sc = avs[csrc[j]] + adn;
        sc = (sc < 0.f) ? 0.2f * sc : sc;
        m = fmaxf(m, sc);
    }
    #pragma unroll
    for (int d = 32; d > 0; d >>= 1) m = fmaxf(m, __shfl_xor(m, d));
    float4 acc = make_float4(0.f, 0.f, 0.f, 0.f);
    float ssum = 0.f;
    int j = beg + half;
    for (; j + 6 < end; j += 8) {
        int s0 = csrc[j], s1 = csrc[j + 2], s2 = csrc[j + 4], s3 = csrc[j + 6];
        float4 h0 = *((const float4*)(h + (size_t)s0 * 128) + sl);
        float4 h1 = *((const float4*)(h + (size_t)s1 * 128) + sl);
        float4 h2 = *((const float4*)(h + (size_t)s2 * 128) + sl);
        float4 h3 = *((const float4*)(h + (size_t)s3 * 128) + sl);
        float sc0 = avs[s0] + adn; sc0 = (sc0 < 0.f) ? 0.2f * sc0 : sc0;
        float sc1 = avs[s1] + adn; sc1 = (sc1 < 0.f) ? 0.2f * sc1 : sc1;
        float sc2 = avs[s2] + adn; sc2 = (sc2 < 0.f) ? 0.2f * sc2 : sc2;
        float sc3 = avs[s3] + adn; sc3 = (sc3 < 0.f) ? 0.2f * sc3 : sc3;
        float e0 = __expf(sc0 - m), e1 = __expf(sc1 - m);
        float e2 = __expf(sc2 - m), e3 = __expf(sc3 - m);
        ssum += (e0 + e1) + (e2 + e3);
        acc.x += e0 * h0.x + e1 * h1.x + e2 * h2.x + e3 * h3.x;
        acc.y += e0 * h0.y + e1 * h1.y + e2 * h2.y + e3 * h3.y;
        acc.z += e0 * h0.z + e1 * h1.z + e2 * h2.z + e3 * h3.z;
        acc.w += e0 * h0.w + e1 * h1.w + e2 * h2.w + e3 * h3.w;
    }
    for (; j < end; j += 2) {
        int s0 = csrc[j];
        float4 h0 = *((const float4*)(h + (size_t)s0 * 128) + sl);
        float sc0 = avs[s0] + adn; sc0 = (sc0 < 0.f) ? 0.2f * sc0 : sc0;
        float e0 = __expf(sc0 - m);
        ssum += e0;
        acc.x += e0 * h0.x;
        acc.y += e0 * h0.y;
        acc.z += e0 * h0.z;
        acc.w += e0 * h0.w;
    }
    ssum  += __shfl_xor(ssum, 32);
    acc.x += __shfl_xor(acc.x, 32);
    acc.y += __shfl_xor(acc.y, 32);
    acc.z += __shfl_xor(acc.z, 32);
    acc.w += __shfl_xor(acc.w, 32);
    if (half == 0) {
        float inv = 1.f / ssum;
        float4 b = ((const float4*)bias)[sl];
        float4 o;
        o.x = fmaxf(acc.x * inv + b.x, 0.f);
        o.y = fmaxf(acc.y * inv + b.y, 0.f);
        o.z = fmaxf(acc.z * inv + b.z, 0.f);
        o.w = fmaxf(acc.w * inv + b.w, 0.f);
        *((float4*)(out + (size_t)w * 128) + sl) = o;
    }
}

// out[n,c] = mid[n,:256] @ Wm2[:,c] + bm2[c]; one wave per node, Wm2 in LDS
__global__ __launch_bounds__(256) void k_mlp2(const float* __restrict__ mid, const float* __restrict__ W2,
                                              const float* __restrict__ b2, float* __restrict__ out, int n) {
    __shared__ float Ws[256 * 6];
    int tid = threadIdx.x;
    for (int t = tid; t < 256 * 6; t += 256) Ws[t] = W2[t];
    __syncthreads();
    int w = (blockIdx.x * 256 + tid) >> 6;
    int lane = tid & 63;
    if (w >= n) return;
    float acc[6];
    float4 mv = ((const float4*)(mid + (size_t)w * 256))[lane];
    int k0 = lane * 4;
    #pragma unroll
    for (int c = 0; c < 6; ++c)
        acc[c] = mv.x * Ws[k0 * 6 + c] + mv.y * Ws[(k0 + 1) * 6 + c]
               + mv.z * Ws[(k0 + 2) * 6 + c] + mv.w * Ws[(k0 + 3) * 6 + c];
    #pragma unroll
    for (int c = 0; c < 6; ++c)
        #pragma unroll
        for (int d = 32; d > 0; d >>= 1) acc[c] += __shfl_down(acc[c], d);
    if (lane == 0) {
        #pragma unroll
        for (int c = 0; c < 6; ++c) out[(size_t)w * 6 + c] = acc[c] + b2[c];
    }
}

extern "C" void kernel_launch(void* const* d_in, const int* in_sizes, int n_in,
                              void* d_out, int out_size, void* d_ws, size_t ws_size,
                              hipStream_t stream) {
    const float* x   = (const float*)d_in[0];
    const int*   ei  = (const int*)d_in[1];
    const float* W[3]    = {(const float*)d_in[2], (const float*)d_in[6], (const float*)d_in[10]};
    const float* bL[3]   = {(const float*)d_in[3], (const float*)d_in[7], (const float*)d_in[11]};
    const float* asr[3]  = {(const float*)d_in[4], (const float*)d_in[8], (const float*)d_in[12]};
    const float* ads[3]  = {(const float*)d_in[5], (const float*)d_in[9], (const float*)d_in[13]};
    const float* Wm1 = (const float*)d_in[14];
    const float* bm1 = (const float*)d_in[15];
    const float* Wm2 = (const float*)d_in[16];
    const float* bm2 = (const float*)d_in[17];
    float* out = (float*)d_out;

    const int N_ = in_sizes[0] / 128;
    const int E_ = in_sizes[1] / 2;
    const int TOT = E_ + N_;
    const int NB = (N_ + 255) / 256;

    char* p = (char*)d_ws;
    auto alloc = [&](size_t bytes) { void* r = (void*)p; p += (bytes + 255) & ~(size_t)255; return r; };
    size_t npad = ((size_t)N_ * 4 + 255) & ~(size_t)255;
    int*   deg  = (int*)alloc(npad);
    int*   cur  = (int*)alloc(npad);
    int*   off  = (int*)alloc((size_t)(N_ + 1) * 4);
    int*   bsum = (int*)alloc((size_t)(NB + 1) * 4);
    int*   csrc = (int*)alloc((size_t)TOT * 4);
    float* avs  = (float*)alloc((size_t)N_ * 4);
    float* avd  = (float*)alloc((size_t)N_ * 4);
    float* buf1 = (float*)alloc((size_t)N_ * 256 * 4);
    float* buf2 = (float*)alloc((size_t)N_ * 128 * 4);

    // ---- CSR build ----
    hipMemsetAsync(deg, 0, npad * 2, stream);   // zero deg AND cur (contiguous)
    k_hist<<<(TOT + 255) / 256, 256, 0, stream>>>(ei, deg, E_, N_);
    k_bsum<<<NB, 256, 0, stream>>>(deg, bsum, N_);
    k_scanb<<<1, 256, 0, stream>>>(bsum, NB);
    k_off<<<NB, 256, 0, stream>>>(deg, bsum, off, N_);
    k_scatter<<<(TOT + 255) / 256, 256, 0, stream>>>(ei, off, cur, csrc, E_, N_);

    const int wave_blocks = (N_ + 3) / 4;
    dim3 gemm_grid(128 / BN, (N_ + BM - 1) / BM);

    // ---- 3 GAT layers ----
    const float* cur_in = x;
    for (int l = 0; l < 3; ++l) {
        k_gemm<<<gemm_grid, 256, 0, stream>>>(cur_in, W[l], nullptr, buf1, N_, 128, 0, 0);
        k_alpha<<<wave_blocks, 256, 0, stream>>>(buf1, asr[l], ads[l], avs, avd, N_);
        k_aggregate<<<wave_blocks, 256, 0, stream>>>(buf1, off, csrc, avs, avd, bL[l], buf2, N_);
        cur_in = buf2;
    }

    // ---- MLP head ----
    dim3 gm1(256 / BN, (N_ + BM - 1) / BM);
    k_gemm<<<gm1, 256, 0, stream>>>(buf2, Wm1, bm1, buf1, N_, 256, 1, 1);
    k_mlp2<<<wave_blocks, 256, 0, stream>>>(buf1, Wm2, bm2, out, N_);
}

// Round 7
// 495.004 us; speedup vs baseline: 1.5434x; 1.1289x over previous
//
#include <hip/hip_runtime.h>
#include <hip/hip_bf16.h>

// GAT (3 layers) + MLP head. N=50000, E=800000 (+N self loops), D=128, H=256, C=6.
// Round 7: R6's bug fixed — k_gemm_gat had c=tid&31 with the {c0,64+c0} column split,
// so Bs[kk][64+c0] read OOB LDS (absmax 2.15). Reverted to R5's proven map
// (g=tid>>4, c=tid&15, BM=128) with the fused fp16-h + alpha epilogue on top.

typedef _Float16 h4 __attribute__((ext_vector_type(4)));   // 8-byte fp16 quad

#define BM 128
#define BN 128
#define BK 16

__global__ __launch_bounds__(256) void k_hist(const int* __restrict__ ei, int* __restrict__ deg,
                                              int E_, int N_) {
    int e = blockIdx.x * 256 + threadIdx.x;
    int total = E_ + N_;
    if (e >= total) return;
    int d = (e < E_) ? ei[E_ + e] : (e - E_);
    atomicAdd(&deg[d], 1);
}

__device__ inline int block_incl_scan(int v, int* wsum) {
    int lane = threadIdx.x & 63, wid = threadIdx.x >> 6;
    #pragma unroll
    for (int d = 1; d < 64; d <<= 1) {
        int t = __shfl_up(v, d);
        if (lane >= d) v += t;
    }
    if (lane == 63) wsum[wid] = v;
    __syncthreads();
    if (wid == 0 && lane < 4) {
        int s = wsum[lane];
        #pragma unroll
        for (int d = 1; d < 4; d <<= 1) {
            int t = __shfl_up(s, d);
            if (lane >= d) s += t;
        }
        wsum[lane] = s;
    }
    __syncthreads();
    if (wid > 0) v += wsum[wid - 1];
    return v;
}

__global__ __launch_bounds__(256) void k_bsum(const int* __restrict__ deg, int* __restrict__ bsum, int n) {
    __shared__ int wsum[4];
    int i = blockIdx.x * 256 + threadIdx.x;
    int v = (i < n) ? deg[i] : 0;
    int lane = threadIdx.x & 63, wid = threadIdx.x >> 6;
    #pragma unroll
    for (int d = 32; d > 0; d >>= 1) v += __shfl_down(v, d);
    if (lane == 0) wsum[wid] = v;
    __syncthreads();
    if (threadIdx.x == 0) bsum[blockIdx.x] = wsum[0] + wsum[1] + wsum[2] + wsum[3];
}

__global__ __launch_bounds__(256) void k_scanb(int* __restrict__ bsum, int nb) {
    __shared__ int wsum[4];
    int i = threadIdx.x;
    int orig = (i < nb) ? bsum[i] : 0;
    int v = block_incl_scan(orig, wsum);
    if (i < nb) bsum[i] = v - orig;
}

__global__ __launch_bounds__(256) void k_off(const int* __restrict__ deg, const int* __restrict__ bsum,
                                             int* __restrict__ off, int n) {
    __shared__ int wsum[4];
    int i = blockIdx.x * 256 + threadIdx.x;
    int orig = (i < n) ? deg[i] : 0;
    int v = block_incl_scan(orig, wsum);
    int base = bsum[blockIdx.x];
    if (i < n) off[i] = base + v - orig;
    if (i == n - 1) off[n] = base + v;
}

__global__ __launch_bounds__(256) void k_scatter(const int* __restrict__ ei, const int* __restrict__ off,
                                                 int* __restrict__ cur, int* __restrict__ csrc,
                                                 int E_, int N_) {
    int e = blockIdx.x * 256 + threadIdx.x;
    int total = E_ + N_;
    if (e >= total) return;
    int s, d;
    if (e < E_) { s = ei[e]; d = ei[E_ + e]; }
    else        { s = e - E_; d = e - E_; }
    int pos = off[d] + atomicAdd(&cur[d], 1);
    csrc[pos] = s;
}

// Layer GEMM: hh[M x 128](fp16) = A[M x 128] @ B[128 x 128]; fused per-row alpha
// dots avs=h.asrc, avd=h.adst (fp32 from acc). 128x128 tile, 256 thr, 8x8/thread.
// Thread (g=tid>>4, c=tid&15): rows {bm+r0..+3, bm+64+r0..+3}, cols {c0..+3, 64+c0..+3}.
__global__ __launch_bounds__(256, 4) void k_gemm_gat(const float* __restrict__ A, const float* __restrict__ B,
                                                     const float* __restrict__ asrc, const float* __restrict__ adst,
                                                     _Float16* __restrict__ hh, float* __restrict__ avs,
                                                     float* __restrict__ avd, int M) {
    __shared__ float As[BK][BM + 4];    // transposed: As[k][m]
    __shared__ float Bs[BK][BN + 4];
    int bm = blockIdx.y * BM;
    int tid = threadIdx.x;
    int g = tid >> 4, c = tid & 15;
    int r0 = g * 4, c0 = c * 4;
    float acc[8][8] = {};
    for (int k0 = 0; k0 < 128; k0 += BK) {
        // stage A: 128 rows x 16 cols, 2 float4/thread, transposed
        #pragma unroll
        for (int i = 0; i < 2; ++i) {
            int idx = i * 256 + tid;
            int row = idx >> 2;
            int j4 = (idx & 3) * 4;
            int grow = bm + row;
            float4 v = make_float4(0.f, 0.f, 0.f, 0.f);
            if (grow < M) v = *(const float4*)(A + (size_t)grow * 128 + k0 + j4);
            As[j4 + 0][row] = v.x;
            As[j4 + 1][row] = v.y;
            As[j4 + 2][row] = v.z;
            As[j4 + 3][row] = v.w;
        }
        // stage B: 16 rows x 128 cols, 2 float4/thread
        #pragma unroll
        for (int i = 0; i < 2; ++i) {
            int idx = i * 256 + tid;
            int br = idx >> 5;
            int bc = (idx & 31) * 4;
            *(float4*)&Bs[br][bc] = *(const float4*)(B + (size_t)(k0 + br) * 128 + bc);
        }
        __syncthreads();
        #pragma unroll
        for (int kk = 0; kk < BK; ++kk) {
            float4 a0 = *(const float4*)&As[kk][r0];
            float4 a1 = *(const float4*)&As[kk][64 + r0];
            float4 b0 = *(const float4*)&Bs[kk][c0];
            float4 b1 = *(const float4*)&Bs[kk][64 + c0];
            float av[8] = {a0.x, a0.y, a0.z, a0.w, a1.x, a1.y, a1.z, a1.w};
            float bv[8] = {b0.x, b0.y, b0.z, b0.w, b1.x, b1.y, b1.z, b1.w};
            #pragma unroll
            for (int x = 0; x < 8; ++x)
                #pragma unroll
                for (int y = 0; y < 8; ++y)
                    acc[x][y] += av[x] * bv[y];
        }
        __syncthreads();
    }
    // epilogue: fp16 h store + fused alpha dots (reduce across the 16 threads of a row group)
    float4 s0v = *(const float4*)(asrc + c0);
    float4 s1v = *(const float4*)(asrc + 64 + c0);
    float4 d0v = *(const float4*)(adst + c0);
    float4 d1v = *(const float4*)(adst + 64 + c0);
    #pragma unroll
    for (int x = 0; x < 8; ++x) {
        int row = bm + ((x < 4) ? (r0 + x) : (64 + r0 + (x - 4)));
        bool ok = row < M;
        if (ok) {
            h4 v0, v1;
            v0.x = (_Float16)acc[x][0]; v0.y = (_Float16)acc[x][1];
            v0.z = (_Float16)acc[x][2]; v0.w = (_Float16)acc[x][3];
            v1.x = (_Float16)acc[x][4]; v1.y = (_Float16)acc[x][5];
            v1.z = (_Float16)acc[x][6]; v1.w = (_Float16)acc[x][7];
            *(h4*)(hh + (size_t)row * 128 + c0)      = v0;
            *(h4*)(hh + (size_t)row * 128 + 64 + c0) = v1;
        }
        float ps = acc[x][0] * s0v.x + acc[x][1] * s0v.y + acc[x][2] * s0v.z + acc[x][3] * s0v.w
                 + acc[x][4] * s1v.x + acc[x][5] * s1v.y + acc[x][6] * s1v.z + acc[x][7] * s1v.w;
        float pd = acc[x][0] * d0v.x + acc[x][1] * d0v.y + acc[x][2] * d0v.z + acc[x][3] * d0v.w
                 + acc[x][4] * d1v.x + acc[x][5] * d1v.y + acc[x][6] * d1v.z + acc[x][7] * d1v.w;
        #pragma unroll
        for (int msk = 1; msk <= 8; msk <<= 1) {   // 16-thread row group: masks 1,2,4,8
            ps += __shfl_xor(ps, msk);
            pd += __shfl_xor(pd, msk);
        }
        if (c == 0 && ok) { avs[row] = ps; avd[row] = pd; }
    }
}

// Generic fp32 GEMM for the MLP (BM=BN=128, BK=16, 8x8/thread). Same as R5.
__global__ __launch_bounds__(256, 4) void k_gemm(const float* __restrict__ A, const float* __restrict__ B,
                                                 const float* __restrict__ bias, float* __restrict__ C,
                                                 int M, int Ncol, int has_bias, int relu) {
    __shared__ float As[BK][BM + 4];
    __shared__ float Bs[BK][BN + 4];
    int bm = blockIdx.y * BM;
    int bn = blockIdx.x * BN;
    int tid = threadIdx.x;
    int g = tid >> 4, c = tid & 15;
    int r0 = g * 4, c0 = c * 4;
    float acc[8][8] = {};
    for (int k0 = 0; k0 < 128; k0 += BK) {
        #pragma unroll
        for (int i = 0; i < 2; ++i) {
            int idx = i * 256 + tid;
            int row = idx >> 2;
            int j4 = (idx & 3) * 4;
            int grow = bm + row;
            float4 v = make_float4(0.f, 0.f, 0.f, 0.f);
            if (grow < M) v = *(const float4*)(A + (size_t)grow * 128 + k0 + j4);
            As[j4 + 0][row] = v.x;
            As[j4 + 1][row] = v.y;
            As[j4 + 2][row] = v.z;
            As[j4 + 3][row] = v.w;
        }
        #pragma unroll
        for (int i = 0; i < 2; ++i) {
            int idx = i * 256 + tid;
            int br = idx >> 5;
            int bc = (idx & 31) * 4;
            *(float4*)&Bs[br][bc] = *(const float4*)(B + (size_t)(k0 + br) * Ncol + bn + bc);
        }
        __syncthreads();
        #pragma unroll
        for (int kk = 0; kk < BK; ++kk) {
            float4 a0 = *(const float4*)&As[kk][r0];
            float4 a1 = *(const float4*)&As[kk][64 + r0];
            float4 b0 = *(const float4*)&Bs[kk][c0];
            float4 b1 = *(const float4*)&Bs[kk][64 + c0];
            float av[8] = {a0.x, a0.y, a0.z, a0.w, a1.x, a1.y, a1.z, a1.w};
            float bv[8] = {b0.x, b0.y, b0.z, b0.w, b1.x, b1.y, b1.z, b1.w};
            #pragma unroll
            for (int x = 0; x < 8; ++x)
                #pragma unroll
                for (int y = 0; y < 8; ++y)
                    acc[x][y] += av[x] * bv[y];
        }
        __syncthreads();
    }
    float4 bvl = make_float4(0.f, 0.f, 0.f, 0.f);
    float4 bvh = make_float4(0.f, 0.f, 0.f, 0.f);
    if (has_bias) {
        bvl = *(const float4*)(bias + bn + c0);
        bvh = *(const float4*)(bias + bn + 64 + c0);
    }
    #pragma unroll
    for (int x = 0; x < 8; ++x) {
        int row = bm + ((x < 4) ? (r0 + x) : (64 + r0 + (x - 4)));
        if (row >= M) continue;
        float4 o0, o1;
        o0.x = acc[x][0] + bvl.x; o0.y = acc[x][1] + bvl.y;
        o0.z = acc[x][2] + bvl.z; o0.w = acc[x][3] + bvl.w;
        o1.x = acc[x][4] + bvh.x; o1.y = acc[x][5] + bvh.y;
        o1.z = acc[x][6] + bvh.z; o1.w = acc[x][7] + bvh.w;
        if (relu) {
            o0.x = fmaxf(o0.x, 0.f); o0.y = fmaxf(o0.y, 0.f);
            o0.z = fmaxf(o0.z, 0.f); o0.w = fmaxf(o0.w, 0.f);
            o1.x = fmaxf(o1.x, 0.f); o1.y = fmaxf(o1.y, 0.f);
            o1.z = fmaxf(o1.z, 0.f); o1.w = fmaxf(o1.w, 0.f);
        }
        *(float4*)(C + (size_t)row * Ncol + bn + c0)      = o0;
        *(float4*)(C + (size_t)row * Ncol + bn + 64 + c0) = o1;
    }
}

// one wave per dst node: 2-pass segment softmax + weighted aggregate + bias + relu.
// Pass 2: half-wave (32 lanes) per edge, fp16 row (256B) loads as h4, 4x unroll.
__global__ __launch_bounds__(256) void k_aggregate(const _Float16* __restrict__ hh, const int* __restrict__ off,
                                                   const int* __restrict__ csrc, const float* __restrict__ avs,
                                                   const float* __restrict__ avd, const float* __restrict__ bias,
                                                   float* __restrict__ out, int n) {
    int w = (blockIdx.x * 256 + threadIdx.x) >> 6;
    int lane = threadIdx.x & 63;
    if (w >= n) return;
    int half = lane >> 5;
    int sl = lane & 31;
    int beg = off[w], end = off[w + 1];
    float adn = avd[w];
    float m = -1e30f;
    for (int j = beg + lane; j < end; j += 64) {
        float sc = avs[csrc[j]] + adn;
        sc = (sc < 0.f) ? 0.2f * sc : sc;
        m = fmaxf(m, sc);
    }
    #pragma unroll
    for (int d = 32; d > 0; d >>= 1) m = fmaxf(m, __shfl_xor(m, d));
    float4 acc = make_float4(0.f, 0.f, 0.f, 0.f);
    float ssum = 0.f;
    int j = beg + half;
    for (; j + 6 < end; j += 8) {
        int s0 = csrc[j], s1 = csrc[j + 2], s2 = csrc[j + 4], s3 = csrc[j + 6];
        h4 h0 = ((const h4*)(hh + (size_t)s0 * 128))[sl];
        h4 h1 = ((const h4*)(hh + (size_t)s1 * 128))[sl];
        h4 h2 = ((const h4*)(hh + (size_t)s2 * 128))[sl];
        h4 h3 = ((const h4*)(hh + (size_t)s3 * 128))[sl];
        float sc0 = avs[s0] + adn; sc0 = (sc0 < 0.f) ? 0.2f * sc0 : sc0;
        float sc1 = avs[s1] + adn; sc1 = (sc1 < 0.f) ? 0.2f * sc1 : sc1;
        float sc2 = avs[s2] + adn; sc2 = (sc2 < 0.f) ? 0.2f * sc2 : sc2;
        float sc3 = avs[s3] + adn; sc3 = (sc3 < 0.f) ? 0.2f * sc3 : sc3;
        float e0 = __expf(sc0 - m), e1 = __expf(sc1 - m);
        float e2 = __expf(sc2 - m), e3 = __expf(sc3 - m);
        ssum += (e0 + e1) + (e2 + e3);
        acc.x += e0 * (float)h0.x + e1 * (float)h1.x + e2 * (float)h2.x + e3 * (float)h3.x;
        acc.y += e0 * (float)h0.y + e1 * (float)h1.y + e2 * (float)h2.y + e3 * (float)h3.y;
        acc.z += e0 * (float)h0.z + e1 * (float)h1.z + e2 * (float)h2.z + e3 * (float)h3.z;
        acc.w += e0 * (float)h0.w + e1 * (float)h1.w + e2 * (float)h2.w + e3 * (float)h3.w;
    }
    for (; j < end; j += 2) {
        int s0 = csrc[j];
        h4 h0 = ((const h4*)(hh + (size_t)s0 * 128))[sl];
        float sc0 = avs[s0] + adn; sc0 = (sc0 < 0.f) ? 0.2f * sc0 : sc0;
        float e0 = __expf(sc0 - m);
        ssum += e0;
        acc.x += e0 * (float)h0.x;
        acc.y += e0 * (float)h0.y;
        acc.z += e0 * (float)h0.z;
        acc.w += e0 * (float)h0.w;
    }
    ssum  += __shfl_xor(ssum, 32);
    acc.x += __shfl_xor(acc.x, 32);
    acc.y += __shfl_xor(acc.y, 32);
    acc.z += __shfl_xor(acc.z, 32);
    acc.w += __shfl_xor(acc.w, 32);
    if (half == 0) {
        float inv = 1.f / ssum;
        float4 b = ((const float4*)bias)[sl];
        float4 o;
        o.x = fmaxf(acc.x * inv + b.x, 0.f);
        o.y = fmaxf(acc.y * inv + b.y, 0.f);
        o.z = fmaxf(acc.z * inv + b.z, 0.f);
        o.w = fmaxf(acc.w * inv + b.w, 0.f);
        *((float4*)(out + (size_t)w * 128) + sl) = o;
    }
}

// out[n,c] = mid[n,:256] @ Wm2[:,c] + bm2[c]; one wave per node, Wm2 in LDS
__global__ __launch_bounds__(256) void k_mlp2(const float* __restrict__ mid, const float* __restrict__ W2,
                                              const float* __restrict__ b2, float* __restrict__ out, int n) {
    __shared__ float Ws[256 * 6];
    int tid = threadIdx.x;
    for (int t = tid; t < 256 * 6; t += 256) Ws[t] = W2[t];
    __syncthreads();
    int w = (blockIdx.x * 256 + tid) >> 6;
    int lane = tid & 63;
    if (w >= n) return;
    float acc[6];
    float4 mv = ((const float4*)(mid + (size_t)w * 256))[lane];
    int k0 = lane * 4;
    #pragma unroll
    for (int c = 0; c < 6; ++c)
        acc[c] = mv.x * Ws[k0 * 6 + c] + mv.y * Ws[(k0 + 1) * 6 + c]
               + mv.z * Ws[(k0 + 2) * 6 + c] + mv.w * Ws[(k0 + 3) * 6 + c];
    #pragma unroll
    for (int c = 0; c < 6; ++c)
        #pragma unroll
        for (int d = 32; d > 0; d >>= 1) acc[c] += __shfl_down(acc[c], d);
    if (lane == 0) {
        #pragma unroll
        for (int c = 0; c < 6; ++c) out[(size_t)w * 6 + c] = acc[c] + b2[c];
    }
}

extern "C" void kernel_launch(void* const* d_in, const int* in_sizes, int n_in,
                              void* d_out, int out_size, void* d_ws, size_t ws_size,
                              hipStream_t stream) {
    const float* x   = (const float*)d_in[0];
    const int*   ei  = (const int*)d_in[1];
    const float* W[3]    = {(const float*)d_in[2], (const float*)d_in[6], (const float*)d_in[10]};
    const float* bL[3]   = {(const float*)d_in[3], (const float*)d_in[7], (const float*)d_in[11]};
    const float* asr[3]  = {(const float*)d_in[4], (const float*)d_in[8], (const float*)d_in[12]};
    const float* ads[3]  = {(const float*)d_in[5], (const float*)d_in[9], (const float*)d_in[13]};
    const float* Wm1 = (const float*)d_in[14];
    const float* bm1 = (const float*)d_in[15];
    const float* Wm2 = (const float*)d_in[16];
    const float* bm2 = (const float*)d_in[17];
    float* out = (float*)d_out;

    const int N_ = in_sizes[0] / 128;
    const int E_ = in_sizes[1] / 2;
    const int TOT = E_ + N_;
    const int NB = (N_ + 255) / 256;

    char* p = (char*)d_ws;
    auto alloc = [&](size_t bytes) { void* r = (void*)p; p += (bytes + 255) & ~(size_t)255; return r; };
    size_t npad = ((size_t)N_ * 4 + 255) & ~(size_t)255;
    int*   deg  = (int*)alloc(npad);
    int*   cur  = (int*)alloc(npad);
    int*   off  = (int*)alloc((size_t)(N_ + 1) * 4);
    int*   bsum = (int*)alloc((size_t)(NB + 1) * 4);
    int*   csrc = (int*)alloc((size_t)TOT * 4);
    float* avs  = (float*)alloc((size_t)N_ * 4);
    float* avd  = (float*)alloc((size_t)N_ * 4);
    float* buf1 = (float*)alloc((size_t)N_ * 256 * 4);   // mid (MLP); fp16 hh aliases it during GAT layers
    float* buf2 = (float*)alloc((size_t)N_ * 128 * 4);
    _Float16* hh = (_Float16*)buf1;                      // N x 128 fp16 = 12.8 MB, fits in buf1

    // ---- CSR build ----
    hipMemsetAsync(deg, 0, npad * 2, stream);
    k_hist<<<(TOT + 255) / 256, 256, 0, stream>>>(ei, deg, E_, N_);
    k_bsum<<<NB, 256, 0, stream>>>(deg, bsum, N_);
    k_scanb<<<1, 256, 0, stream>>>(bsum, NB);
    k_off<<<NB, 256, 0, stream>>>(deg, bsum, off, N_);
    k_scatter<<<(TOT + 255) / 256, 256, 0, stream>>>(ei, off, cur, csrc, E_, N_);

    const int wave_blocks = (N_ + 3) / 4;
    dim3 gat_grid(1, (N_ + BM - 1) / BM);

    // ---- 3 GAT layers ----
    const float* cur_in = x;
    for (int l = 0; l < 3; ++l) {
        k_gemm_gat<<<gat_grid, 256, 0, stream>>>(cur_in, W[l], asr[l], ads[l], hh, avs, avd, N_);
        k_aggregate<<<wave_blocks, 256, 0, stream>>>(hh, off, csrc, avs, avd, bL[l], buf2, N_);
        cur_in = buf2;
    }

    // ---- MLP head ----
    dim3 gm1(256 / BN, (N_ + BM - 1) / BM);
    k_gemm<<<gm1, 256, 0, stream>>>(buf2, Wm1, bm1, buf1, N_, 256, 1, 1);
    k_mlp2<<<wave_blocks, 256, 0, stream>>>(buf1, Wm2, bm2, out, N_);
}

// Round 8
// 406.852 us; speedup vs baseline: 1.8778x; 1.2167x over previous
//
#include <hip/hip_runtime.h>
#include <hip/hip_bf16.h>

// GAT (3 layers) + MLP head. N=50000, E=800000 (+N self loops), D=128, H=256, C=6.
// Round 8: MFMA (f32_16x16x32_f16) GEMMs. x and aggregate outputs stored fp16;
// weights pre-transposed to fp16 Wt[n][k] once per launch. Both MFMA operands
// load as contiguous half8 (ds_read_b128, LDA=136 pad -> conflict-free).
// Fragment maps (verified, learn_hip m89/m91): A/B frag[l] = M^T[l&15][quad*8+j];
// D: row=quad*4+reg, col=lane&15. mid stays fp32 for final-matmul accuracy.

typedef _Float16 h4 __attribute__((ext_vector_type(4)));
typedef _Float16 half8 __attribute__((ext_vector_type(8)));
typedef float f32x4 __attribute__((ext_vector_type(4)));

#define LDA 136   // padded fp16 row stride (272B: bank rotation by 4/row)

__global__ __launch_bounds__(256) void k_hist(const int* __restrict__ ei, int* __restrict__ deg,
                                              int E_, int N_) {
    int e = blockIdx.x * 256 + threadIdx.x;
    int total = E_ + N_;
    if (e >= total) return;
    int d = (e < E_) ? ei[E_ + e] : (e - E_);
    atomicAdd(&deg[d], 1);
}

__device__ inline int block_incl_scan(int v, int* wsum) {
    int lane = threadIdx.x & 63, wid = threadIdx.x >> 6;
    #pragma unroll
    for (int d = 1; d < 64; d <<= 1) {
        int t = __shfl_up(v, d);
        if (lane >= d) v += t;
    }
    if (lane == 63) wsum[wid] = v;
    __syncthreads();
    if (wid == 0 && lane < 4) {
        int s = wsum[lane];
        #pragma unroll
        for (int d = 1; d < 4; d <<= 1) {
            int t = __shfl_up(s, d);
            if (lane >= d) s += t;
        }
        wsum[lane] = s;
    }
    __syncthreads();
    if (wid > 0) v += wsum[wid - 1];
    return v;
}

__global__ __launch_bounds__(256) void k_bsum(const int* __restrict__ deg, int* __restrict__ bsum, int n) {
    __shared__ int wsum[4];
    int i = blockIdx.x * 256 + threadIdx.x;
    int v = (i < n) ? deg[i] : 0;
    int lane = threadIdx.x & 63, wid = threadIdx.x >> 6;
    #pragma unroll
    for (int d = 32; d > 0; d >>= 1) v += __shfl_down(v, d);
    if (lane == 0) wsum[wid] = v;
    __syncthreads();
    if (threadIdx.x == 0) bsum[blockIdx.x] = wsum[0] + wsum[1] + wsum[2] + wsum[3];
}

__global__ __launch_bounds__(256) void k_scanb(int* __restrict__ bsum, int nb) {
    __shared__ int wsum[4];
    int i = threadIdx.x;
    int orig = (i < nb) ? bsum[i] : 0;
    int v = block_incl_scan(orig, wsum);
    if (i < nb) bsum[i] = v - orig;
}

__global__ __launch_bounds__(256) void k_off(const int* __restrict__ deg, const int* __restrict__ bsum,
                                             int* __restrict__ off, int n) {
    __shared__ int wsum[4];
    int i = blockIdx.x * 256 + threadIdx.x;
    int orig = (i < n) ? deg[i] : 0;
    int v = block_incl_scan(orig, wsum);
    int base = bsum[blockIdx.x];
    if (i < n) off[i] = base + v - orig;
    if (i == n - 1) off[n] = base + v;
}

__global__ __launch_bounds__(256) void k_scatter(const int* __restrict__ ei, const int* __restrict__ off,
                                                 int* __restrict__ cur, int* __restrict__ csrc,
                                                 int E_, int N_) {
    int e = blockIdx.x * 256 + threadIdx.x;
    int total = E_ + N_;
    if (e >= total) return;
    int s, d;
    if (e < E_) { s = ei[e]; d = ei[E_ + e]; }
    else        { s = e - E_; d = e - E_; }
    int pos = off[d] + atomicAdd(&cur[d], 1);
    csrc[pos] = s;
}

// x (fp32) -> xh (fp16), 4 elems/thread
__global__ __launch_bounds__(256) void k_cvt(const float* __restrict__ x, _Float16* __restrict__ xh, int n4) {
    int i = blockIdx.x * 256 + threadIdx.x;
    if (i >= n4) return;
    float4 v = ((const float4*)x)[i];
    h4 o;
    o.x = (_Float16)v.x; o.y = (_Float16)v.y; o.z = (_Float16)v.z; o.w = (_Float16)v.w;
    ((h4*)xh)[i] = o;
}

// transpose+convert the three 128x128 layer weights: Wt[seg][n*128+k] = W[k*128+n]
__global__ __launch_bounds__(256) void k_wt3(const float* __restrict__ W0, const float* __restrict__ W1,
                                             const float* __restrict__ W2, _Float16* __restrict__ Wt) {
    int i = blockIdx.x * 256 + threadIdx.x;     // 0..49151
    if (i >= 3 * 16384) return;
    int seg = i >> 14;
    int j = i & 16383;
    const float* W = (seg == 0) ? W0 : (seg == 1) ? W1 : W2;
    int n = j >> 7, k = j & 127;
    Wt[i] = (_Float16)W[k * 128 + n];
}

// transpose+convert Wm1 (128x256): Wt[n*128+k] = W[k*256+n]
__global__ __launch_bounds__(256) void k_wt1(const float* __restrict__ W, _Float16* __restrict__ Wt) {
    int i = blockIdx.x * 256 + threadIdx.x;     // 0..32767
    if (i >= 32768) return;
    int n = i >> 7, k = i & 127;
    Wt[i] = (_Float16)W[k * 256 + n];
}

// Layer GEMM via MFMA: hh[M x 128](fp16) = A16[M x 128] @ W (Wt = W^T fp16) with
// fused alpha dots avs = h.asrc, avd = h.adst (fp32 acc). Block: 64 rows, 4 waves.
__global__ __launch_bounds__(256, 3) void k_mfma_gat(const _Float16* __restrict__ A16,
        const _Float16* __restrict__ Wt, const float* __restrict__ asrc, const float* __restrict__ adst,
        _Float16* __restrict__ hh, float* __restrict__ avs, float* __restrict__ avd, int M) {
    __shared__ _Float16 As[64 * LDA];
    __shared__ _Float16 Bs[128 * LDA];
    int tid = threadIdx.x;
    int bm = blockIdx.x * 64;
    // stage A: 64 rows x 16 chunks of 16B
    #pragma unroll
    for (int i = 0; i < 4; ++i) {
        int idx = i * 256 + tid;
        int row = idx >> 4, c16 = idx & 15;
        int gr = bm + row;
        uint4 v = make_uint4(0u, 0u, 0u, 0u);
        if (gr < M) v = *(const uint4*)(A16 + (size_t)gr * 128 + c16 * 8);
        *(uint4*)&As[row * LDA + c16 * 8] = v;
    }
    // stage Wt: 128 rows x 16 chunks
    #pragma unroll
    for (int i = 0; i < 8; ++i) {
        int idx = i * 256 + tid;
        int row = idx >> 4, c16 = idx & 15;
        *(uint4*)&Bs[row * LDA + c16 * 8] = *(const uint4*)(Wt + (size_t)row * 128 + c16 * 8);
    }
    __syncthreads();
    int w = tid >> 6, l = tid & 63;
    int quad = l >> 4, cl = l & 15;
    f32x4 acc[8] = {};
    const _Float16* ap = &As[(w * 16 + cl) * LDA + quad * 8];
    #pragma unroll
    for (int kt = 0; kt < 4; ++kt) {
        half8 a = *(const half8*)(ap + kt * 32);
        #pragma unroll
        for (int ct = 0; ct < 8; ++ct) {
            half8 b = *(const half8*)&Bs[(ct * 16 + cl) * LDA + kt * 32 + quad * 8];
            acc[ct] = __builtin_amdgcn_mfma_f32_16x16x32_f16(a, b, acc[ct], 0, 0, 0);
        }
    }
    // epilogue: fp16 h store + alpha dots (reduce over the 16 lanes of each quad)
    float sa[8], da[8];
    #pragma unroll
    for (int ct = 0; ct < 8; ++ct) { sa[ct] = asrc[ct * 16 + cl]; da[ct] = adst[ct * 16 + cl]; }
    #pragma unroll
    for (int r = 0; r < 4; ++r) {
        int row = bm + w * 16 + quad * 4 + r;
        bool ok = row < M;
        float ps = 0.f, pd = 0.f;
        #pragma unroll
        for (int ct = 0; ct < 8; ++ct) {
            float v = acc[ct][r];
            if (ok) hh[(size_t)row * 128 + ct * 16 + cl] = (_Float16)v;
            ps += v * sa[ct];
            pd += v * da[ct];
        }
        #pragma unroll
        for (int msk = 1; msk <= 8; msk <<= 1) { ps += __shfl_xor(ps, msk); pd += __shfl_xor(pd, msk); }
        if (cl == 0 && ok) { avs[row] = ps; avd[row] = pd; }
    }
}

// MLP GEMM via MFMA: mid[M x 256](fp32) = relu(A16[M x 128] @ Wm1 + bm1).
// grid (2, M/64): blockIdx.x picks the 128-col half of Wm1t.
__global__ __launch_bounds__(256, 3) void k_mfma_mlp(const _Float16* __restrict__ A16,
        const _Float16* __restrict__ Wt, const float* __restrict__ bias, float* __restrict__ C, int M) {
    __shared__ _Float16 As[64 * LDA];
    __shared__ _Float16 Bs[128 * LDA];
    int tid = threadIdx.x;
    int bm = blockIdx.y * 64;
    int bn = blockIdx.x * 128;
    #pragma unroll
    for (int i = 0; i < 4; ++i) {
        int idx = i * 256 + tid;
        int row = idx >> 4, c16 = idx & 15;
        int gr = bm + row;
        uint4 v = make_uint4(0u, 0u, 0u, 0u);
        if (gr < M) v = *(const uint4*)(A16 + (size_t)gr * 128 + c16 * 8);
        *(uint4*)&As[row * LDA + c16 * 8] = v;
    }
    #pragma unroll
    for (int i = 0; i < 8; ++i) {
        int idx = i * 256 + tid;
        int row = idx >> 4, c16 = idx & 15;
        *(uint4*)&Bs[row * LDA + c16 * 8] = *(const uint4*)(Wt + (size_t)(bn + row) * 128 + c16 * 8);
    }
    __syncthreads();
    int w = tid >> 6, l = tid & 63;
    int quad = l >> 4, cl = l & 15;
    f32x4 acc[8] = {};
    const _Float16* ap = &As[(w * 16 + cl) * LDA + quad * 8];
    #pragma unroll
    for (int kt = 0; kt < 4; ++kt) {
        half8 a = *(const half8*)(ap + kt * 32);
        #pragma unroll
        for (int ct = 0; ct < 8; ++ct) {
            half8 b = *(const half8*)&Bs[(ct * 16 + cl) * LDA + kt * 32 + quad * 8];
            acc[ct] = __builtin_amdgcn_mfma_f32_16x16x32_f16(a, b, acc[ct], 0, 0, 0);
        }
    }
    float bs[8];
    #pragma unroll
    for (int ct = 0; ct < 8; ++ct) bs[ct] = bias[bn + ct * 16 + cl];
    #pragma unroll
    for (int r = 0; r < 4; ++r) {
        int row = bm + w * 16 + quad * 4 + r;
        if (row >= M) continue;
        #pragma unroll
        for (int ct = 0; ct < 8; ++ct)
            C[(size_t)row * 256 + bn + ct * 16 + cl] = fmaxf(acc[ct][r] + bs[ct], 0.f);
    }
}

// one wave per dst node: 2-pass segment softmax + weighted aggregate + bias + relu.
// Pass 2: half-wave per edge, fp16 rows, 4x unroll. Output written fp16 (next GEMM's A).
__global__ __launch_bounds__(256) void k_aggregate(const _Float16* __restrict__ hh, const int* __restrict__ off,
                                                   const int* __restrict__ csrc, const float* __restrict__ avs,
                                                   const float* __restrict__ avd, const float* __restrict__ bias,
                                                   _Float16* __restrict__ outh, int n) {
    int w = (blockIdx.x * 256 + threadIdx.x) >> 6;
    int lane = threadIdx.x & 63;
    if (w >= n) return;
    int half = lane >> 5;
    int sl = lane & 31;
    int beg = off[w], end = off[w + 1];
    float adn = avd[w];
    float m = -1e30f;
    for (int j = beg + lane; j < end; j += 64) {
        float sc = avs[csrc[j]] + adn;
        sc = (sc < 0.f) ? 0.2f * sc : sc;
        m = fmaxf(m, sc);
    }
    #pragma unroll
    for (int d = 32; d > 0; d >>= 1) m = fmaxf(m, __shfl_xor(m, d));
    float4 acc = make_float4(0.f, 0.f, 0.f, 0.f);
    float ssum = 0.f;
    int j = beg + half;
    for (; j + 6 < end; j += 8) {
        int s0 = csrc[j], s1 = csrc[j + 2], s2 = csrc[j + 4], s3 = csrc[j + 6];
        h4 h0 = ((const h4*)(hh + (size_t)s0 * 128))[sl];
        h4 h1 = ((const h4*)(hh + (size_t)s1 * 128))[sl];
        h4 h2 = ((const h4*)(hh + (size_t)s2 * 128))[sl];
        h4 h3 = ((const h4*)(hh + (size_t)s3 * 128))[sl];
        float sc0 = avs[s0] + adn; sc0 = (sc0 < 0.f) ? 0.2f * sc0 : sc0;
        float sc1 = avs[s1] + adn; sc1 = (sc1 < 0.f) ? 0.2f * sc1 : sc1;
        float sc2 = avs[s2] + adn; sc2 = (sc2 < 0.f) ? 0.2f * sc2 : sc2;
        float sc3 = avs[s3] + adn; sc3 = (sc3 < 0.f) ? 0.2f * sc3 : sc3;
        float e0 = __expf(sc0 - m), e1 = __expf(sc1 - m);
        float e2 = __expf(sc2 - m), e3 = __expf(sc3 - m);
        ssum += (e0 + e1) + (e2 + e3);
        acc.x += e0 * (float)h0.x + e1 * (float)h1.x + e2 * (float)h2.x + e3 * (float)h3.x;
        acc.y += e0 * (float)h0.y + e1 * (float)h1.y + e2 * (float)h2.y + e3 * (float)h3.y;
        acc.z += e0 * (float)h0.z + e1 * (float)h1.z + e2 * (float)h2.z + e3 * (float)h3.z;
        acc.w += e0 * (float)h0.w + e1 * (float)h1.w + e2 * (float)h2.w + e3 * (float)h3.w;
    }
    for (; j < end; j += 2) {
        int s0 = csrc[j];
        h4 h0 = ((const h4*)(hh + (size_t)s0 * 128))[sl];
        float sc0 = avs[s0] + adn; sc0 = (sc0 < 0.f) ? 0.2f * sc0 : sc0;
        float e0 = __expf(sc0 - m);
        ssum += e0;
        acc.x += e0 * (float)h0.x;
        acc.y += e0 * (float)h0.y;
        acc.z += e0 * (float)h0.z;
        acc.w += e0 * (float)h0.w;
    }
    ssum  += __shfl_xor(ssum, 32);
    acc.x += __shfl_xor(acc.x, 32);
    acc.y += __shfl_xor(acc.y, 32);
    acc.z += __shfl_xor(acc.z, 32);
    acc.w += __shfl_xor(acc.w, 32);
    if (half == 0) {
        float inv = 1.f / ssum;
        float4 b = ((const float4*)bias)[sl];
        h4 o;
        o.x = (_Float16)fmaxf(acc.x * inv + b.x, 0.f);
        o.y = (_Float16)fmaxf(acc.y * inv + b.y, 0.f);
        o.z = (_Float16)fmaxf(acc.z * inv + b.z, 0.f);
        o.w = (_Float16)fmaxf(acc.w * inv + b.w, 0.f);
        *((h4*)(outh + (size_t)w * 128) + sl) = o;
    }
}

// out[n,c] = mid[n,:256] @ Wm2[:,c] + bm2[c]; one wave per node, Wm2 in LDS
__global__ __launch_bounds__(256) void k_mlp2(const float* __restrict__ mid, const float* __restrict__ W2,
                                              const float* __restrict__ b2, float* __restrict__ out, int n) {
    __shared__ float Ws[256 * 6];
    int tid = threadIdx.x;
    for (int t = tid; t < 256 * 6; t += 256) Ws[t] = W2[t];
    __syncthreads();
    int w = (blockIdx.x * 256 + tid) >> 6;
    int lane = tid & 63;
    if (w >= n) return;
    float acc[6];
    float4 mv = ((const float4*)(mid + (size_t)w * 256))[lane];
    int k0 = lane * 4;
    #pragma unroll
    for (int c = 0; c < 6; ++c)
        acc[c] = mv.x * Ws[k0 * 6 + c] + mv.y * Ws[(k0 + 1) * 6 + c]
               + mv.z * Ws[(k0 + 2) * 6 + c] + mv.w * Ws[(k0 + 3) * 6 + c];
    #pragma unroll
    for (int c = 0; c < 6; ++c)
        #pragma unroll
        for (int d = 32; d > 0; d >>= 1) acc[c] += __shfl_down(acc[c], d);
    if (lane == 0) {
        #pragma unroll
        for (int c = 0; c < 6; ++c) out[(size_t)w * 6 + c] = acc[c] + b2[c];
    }
}

extern "C" void kernel_launch(void* const* d_in, const int* in_sizes, int n_in,
                              void* d_out, int out_size, void* d_ws, size_t ws_size,
                              hipStream_t stream) {
    const float* x   = (const float*)d_in[0];
    const int*   ei  = (const int*)d_in[1];
    const float* W[3]    = {(const float*)d_in[2], (const float*)d_in[6], (const float*)d_in[10]};
    const float* bL[3]   = {(const float*)d_in[3], (const float*)d_in[7], (const float*)d_in[11]};
    const float* asr[3]  = {(const float*)d_in[4], (const float*)d_in[8], (const float*)d_in[12]};
    const float* ads[3]  = {(const float*)d_in[5], (const float*)d_in[9], (const float*)d_in[13]};
    const float* Wm1 = (const float*)d_in[14];
    const float* bm1 = (const float*)d_in[15];
    const float* Wm2 = (const float*)d_in[16];
    const float* bm2 = (const float*)d_in[17];
    float* out = (float*)d_out;

    const int N_ = in_sizes[0] / 128;
    const int E_ = in_sizes[1] / 2;
    const int TOT = E_ + N_;
    const int NB = (N_ + 255) / 256;

    char* p = (char*)d_ws;
    auto alloc = [&](size_t bytes) { void* r = (void*)p; p += (bytes + 255) & ~(size_t)255; return r; };
    size_t npad = ((size_t)N_ * 4 + 255) & ~(size_t)255;
    int*   deg  = (int*)alloc(npad);
    int*   cur  = (int*)alloc(npad);
    int*   off  = (int*)alloc((size_t)(N_ + 1) * 4);
    int*   bsum = (int*)alloc((size_t)(NB + 1) * 4);
    int*   csrc = (int*)alloc((size_t)TOT * 4);
    float* avs  = (float*)alloc((size_t)N_ * 4);
    float* avd  = (float*)alloc((size_t)N_ * 4);
    _Float16* Wt3  = (_Float16*)alloc(3 * 16384 * 2);    // W0^T,W1^T,W2^T fp16
    _Float16* Wm1t = (_Float16*)alloc(32768 * 2);        // Wm1^T fp16 [256][128]
    _Float16* xh   = (_Float16*)alloc((size_t)N_ * 128 * 2);
    _Float16* agg  = (_Float16*)alloc((size_t)N_ * 128 * 2);
    float*    mid  = (float*)alloc((size_t)N_ * 256 * 4);
    _Float16* hh   = (_Float16*)mid;   // hh (layers) aliases mid (MLP phase) — disjoint in time

    // ---- CSR build + precision prep ----
    hipMemsetAsync(deg, 0, npad * 2, stream);
    k_hist<<<(TOT + 255) / 256, 256, 0, stream>>>(ei, deg, E_, N_);
    k_bsum<<<NB, 256, 0, stream>>>(deg, bsum, N_);
    k_scanb<<<1, 256, 0, stream>>>(bsum, NB);
    k_off<<<NB, 256, 0, stream>>>(deg, bsum, off, N_);
    k_scatter<<<(TOT + 255) / 256, 256, 0, stream>>>(ei, off, cur, csrc, E_, N_);
    k_cvt<<<(N_ * 32 + 255) / 256, 256, 0, stream>>>(x, xh, N_ * 32);   // N*128/4 quads
    k_wt3<<<192, 256, 0, stream>>>(W[0], W[1], W[2], Wt3);
    k_wt1<<<128, 256, 0, stream>>>(Wm1, Wm1t);

    const int wave_blocks = (N_ + 3) / 4;
    const int gat_blocks = (N_ + 63) / 64;

    // ---- 3 GAT layers ----
    const _Float16* cur_in = xh;
    for (int l = 0; l < 3; ++l) {
        k_mfma_gat<<<gat_blocks, 256, 0, stream>>>(cur_in, Wt3 + l * 16384, asr[l], ads[l],
                                                   hh, avs, avd, N_);
        k_aggregate<<<wave_blocks, 256, 0, stream>>>(hh, off, csrc, avs, avd, bL[l], agg, N_);
        cur_in = agg;
    }

    // ---- MLP head ----
    dim3 gm1(2, gat_blocks);
    k_mfma_mlp<<<gm1, 256, 0, stream>>>(agg, Wm1t, bm1, mid, N_);
    k_mlp2<<<wave_blocks, 256, 0, stream>>>(mid, Wm2, bm2, out, N_);
}

// Round 9
// 377.913 us; speedup vs baseline: 2.0216x; 1.0766x over previous
//
#include <hip/hip_runtime.h>
#include <hip/hip_bf16.h>

// GAT (3 layers) + MLP head. N=50000, E=800000 (+N self loops), D=128, H=256, C=6.
// Round 9: (1) scatter atomic removed — k_hist's atomicAdd return value is the
// edge's rank (coalesced store); k_scatter becomes pure random write.
// (2) aggregate computes each edge's softmax weight ONCE (edge-parallel pass 1
// into per-wave LDS) instead of 32x redundantly per half-wave; pass 2 reads the
// weight via broadcast ds_read. Fallback to inline path for degree > 256.

typedef _Float16 h4 __attribute__((ext_vector_type(4)));
typedef _Float16 half8 __attribute__((ext_vector_type(8)));
typedef float f32x4 __attribute__((ext_vector_type(4)));

#define LDA 136   // padded fp16 row stride for MFMA staging
#define DCAP 256  // max degree handled by the LDS fast path

__global__ __launch_bounds__(256) void k_hist(const int* __restrict__ ei, int* __restrict__ deg,
                                              int* __restrict__ rank, int E_, int N_) {
    int e = blockIdx.x * 256 + threadIdx.x;
    int total = E_ + N_;
    if (e >= total) return;
    int d = (e < E_) ? ei[E_ + e] : (e - E_);
    rank[e] = atomicAdd(&deg[d], 1);
}

__device__ inline int block_incl_scan(int v, int* wsum) {
    int lane = threadIdx.x & 63, wid = threadIdx.x >> 6;
    #pragma unroll
    for (int d = 1; d < 64; d <<= 1) {
        int t = __shfl_up(v, d);
        if (lane >= d) v += t;
    }
    if (lane == 63) wsum[wid] = v;
    __syncthreads();
    if (wid == 0 && lane < 4) {
        int s = wsum[lane];
        #pragma unroll
        for (int d = 1; d < 4; d <<= 1) {
            int t = __shfl_up(s, d);
            if (lane >= d) s += t;
        }
        wsum[lane] = s;
    }
    __syncthreads();
    if (wid > 0) v += wsum[wid - 1];
    return v;
}

__global__ __launch_bounds__(256) void k_bsum(const int* __restrict__ deg, int* __restrict__ bsum, int n) {
    __shared__ int wsum[4];
    int i = blockIdx.x * 256 + threadIdx.x;
    int v = (i < n) ? deg[i] : 0;
    int lane = threadIdx.x & 63, wid = threadIdx.x >> 6;
    #pragma unroll
    for (int d = 32; d > 0; d >>= 1) v += __shfl_down(v, d);
    if (lane == 0) wsum[wid] = v;
    __syncthreads();
    if (threadIdx.x == 0) bsum[blockIdx.x] = wsum[0] + wsum[1] + wsum[2] + wsum[3];
}

__global__ __launch_bounds__(256) void k_scanb(int* __restrict__ bsum, int nb) {
    __shared__ int wsum[4];
    int i = threadIdx.x;
    int orig = (i < nb) ? bsum[i] : 0;
    int v = block_incl_scan(orig, wsum);
    if (i < nb) bsum[i] = v - orig;
}

__global__ __launch_bounds__(256) void k_off(const int* __restrict__ deg, const int* __restrict__ bsum,
                                             int* __restrict__ off, int n) {
    __shared__ int wsum[4];
    int i = blockIdx.x * 256 + threadIdx.x;
    int orig = (i < n) ? deg[i] : 0;
    int v = block_incl_scan(orig, wsum);
    int base = bsum[blockIdx.x];
    if (i < n) off[i] = base + v - orig;
    if (i == n - 1) off[n] = base + v;
}

// no atomic: pos = off[d] + precomputed rank
__global__ __launch_bounds__(256) void k_scatter(const int* __restrict__ ei, const int* __restrict__ off,
                                                 const int* __restrict__ rank, int* __restrict__ csrc,
                                                 int E_, int N_) {
    int e = blockIdx.x * 256 + threadIdx.x;
    int total = E_ + N_;
    if (e >= total) return;
    int s, d;
    if (e < E_) { s = ei[e]; d = ei[E_ + e]; }
    else        { s = e - E_; d = e - E_; }
    csrc[off[d] + rank[e]] = s;
}

// x (fp32) -> xh (fp16), 4 elems/thread
__global__ __launch_bounds__(256) void k_cvt(const float* __restrict__ x, _Float16* __restrict__ xh, int n4) {
    int i = blockIdx.x * 256 + threadIdx.x;
    if (i >= n4) return;
    float4 v = ((const float4*)x)[i];
    h4 o;
    o.x = (_Float16)v.x; o.y = (_Float16)v.y; o.z = (_Float16)v.z; o.w = (_Float16)v.w;
    ((h4*)xh)[i] = o;
}

// transpose+convert the three 128x128 layer weights: Wt[seg][n*128+k] = W[k*128+n]
__global__ __launch_bounds__(256) void k_wt3(const float* __restrict__ W0, const float* __restrict__ W1,
                                             const float* __restrict__ W2, _Float16* __restrict__ Wt) {
    int i = blockIdx.x * 256 + threadIdx.x;
    if (i >= 3 * 16384) return;
    int seg = i >> 14;
    int j = i & 16383;
    const float* W = (seg == 0) ? W0 : (seg == 1) ? W1 : W2;
    int n = j >> 7, k = j & 127;
    Wt[i] = (_Float16)W[k * 128 + n];
}

// transpose+convert Wm1 (128x256): Wt[n*128+k] = W[k*256+n]
__global__ __launch_bounds__(256) void k_wt1(const float* __restrict__ W, _Float16* __restrict__ Wt) {
    int i = blockIdx.x * 256 + threadIdx.x;
    if (i >= 32768) return;
    int n = i >> 7, k = i & 127;
    Wt[i] = (_Float16)W[k * 256 + n];
}

// Layer GEMM via MFMA: hh[M x 128](fp16) = A16[M x 128] @ W + fused alpha dots.
__global__ __launch_bounds__(256, 3) void k_mfma_gat(const _Float16* __restrict__ A16,
        const _Float16* __restrict__ Wt, const float* __restrict__ asrc, const float* __restrict__ adst,
        _Float16* __restrict__ hh, float* __restrict__ avs, float* __restrict__ avd, int M) {
    __shared__ _Float16 As[64 * LDA];
    __shared__ _Float16 Bs[128 * LDA];
    int tid = threadIdx.x;
    int bm = blockIdx.x * 64;
    #pragma unroll
    for (int i = 0; i < 4; ++i) {
        int idx = i * 256 + tid;
        int row = idx >> 4, c16 = idx & 15;
        int gr = bm + row;
        uint4 v = make_uint4(0u, 0u, 0u, 0u);
        if (gr < M) v = *(const uint4*)(A16 + (size_t)gr * 128 + c16 * 8);
        *(uint4*)&As[row * LDA + c16 * 8] = v;
    }
    #pragma unroll
    for (int i = 0; i < 8; ++i) {
        int idx = i * 256 + tid;
        int row = idx >> 4, c16 = idx & 15;
        *(uint4*)&Bs[row * LDA + c16 * 8] = *(const uint4*)(Wt + (size_t)row * 128 + c16 * 8);
    }
    __syncthreads();
    int w = tid >> 6, l = tid & 63;
    int quad = l >> 4, cl = l & 15;
    f32x4 acc[8] = {};
    const _Float16* ap = &As[(w * 16 + cl) * LDA + quad * 8];
    #pragma unroll
    for (int kt = 0; kt < 4; ++kt) {
        half8 a = *(const half8*)(ap + kt * 32);
        #pragma unroll
        for (int ct = 0; ct < 8; ++ct) {
            half8 b = *(const half8*)&Bs[(ct * 16 + cl) * LDA + kt * 32 + quad * 8];
            acc[ct] = __builtin_amdgcn_mfma_f32_16x16x32_f16(a, b, acc[ct], 0, 0, 0);
        }
    }
    float sa[8], da[8];
    #pragma unroll
    for (int ct = 0; ct < 8; ++ct) { sa[ct] = asrc[ct * 16 + cl]; da[ct] = adst[ct * 16 + cl]; }
    #pragma unroll
    for (int r = 0; r < 4; ++r) {
        int row = bm + w * 16 + quad * 4 + r;
        bool ok = row < M;
        float ps = 0.f, pd = 0.f;
        #pragma unroll
        for (int ct = 0; ct < 8; ++ct) {
            float v = acc[ct][r];
            if (ok) hh[(size_t)row * 128 + ct * 16 + cl] = (_Float16)v;
            ps += v * sa[ct];
            pd += v * da[ct];
        }
        #pragma unroll
        for (int msk = 1; msk <= 8; msk <<= 1) { ps += __shfl_xor(ps, msk); pd += __shfl_xor(pd, msk); }
        if (cl == 0 && ok) { avs[row] = ps; avd[row] = pd; }
    }
}

// MLP GEMM via MFMA: mid[M x 256](fp32) = relu(A16 @ Wm1 + bm1). grid (2, M/64).
__global__ __launch_bounds__(256, 3) void k_mfma_mlp(const _Float16* __restrict__ A16,
        const _Float16* __restrict__ Wt, const float* __restrict__ bias, float* __restrict__ C, int M) {
    __shared__ _Float16 As[64 * LDA];
    __shared__ _Float16 Bs[128 * LDA];
    int tid = threadIdx.x;
    int bm = blockIdx.y * 64;
    int bn = blockIdx.x * 128;
    #pragma unroll
    for (int i = 0; i < 4; ++i) {
        int idx = i * 256 + tid;
        int row = idx >> 4, c16 = idx & 15;
        int gr = bm + row;
        uint4 v = make_uint4(0u, 0u, 0u, 0u);
        if (gr < M) v = *(const uint4*)(A16 + (size_t)gr * 128 + c16 * 8);
        *(uint4*)&As[row * LDA + c16 * 8] = v;
    }
    #pragma unroll
    for (int i = 0; i < 8; ++i) {
        int idx = i * 256 + tid;
        int row = idx >> 4, c16 = idx & 15;
        *(uint4*)&Bs[row * LDA + c16 * 8] = *(const uint4*)(Wt + (size_t)(bn + row) * 128 + c16 * 8);
    }
    __syncthreads();
    int w = tid >> 6, l = tid & 63;
    int quad = l >> 4, cl = l & 15;
    f32x4 acc[8] = {};
    const _Float16* ap = &As[(w * 16 + cl) * LDA + quad * 8];
    #pragma unroll
    for (int kt = 0; kt < 4; ++kt) {
        half8 a = *(const half8*)(ap + kt * 32);
        #pragma unroll
        for (int ct = 0; ct < 8; ++ct) {
            half8 b = *(const half8*)&Bs[(ct * 16 + cl) * LDA + kt * 32 + quad * 8];
            acc[ct] = __builtin_amdgcn_mfma_f32_16x16x32_f16(a, b, acc[ct], 0, 0, 0);
        }
    }
    float bs[8];
    #pragma unroll
    for (int ct = 0; ct < 8; ++ct) bs[ct] = bias[bn + ct * 16 + cl];
    #pragma unroll
    for (int r = 0; r < 4; ++r) {
        int row = bm + w * 16 + quad * 4 + r;
        if (row >= M) continue;
        #pragma unroll
        for (int ct = 0; ct < 8; ++ct)
            C[(size_t)row * 256 + bn + ct * 16 + cl] = fmaxf(acc[ct][r] + bs[ct], 0.f);
    }
}

// one wave per dst node. Pass 1 (edge-parallel over 64 lanes): score -> LDS,
// reduce max, exp -> LDS, reduce sum. Pass 2: half-wave per edge, weight via
// broadcast ds_read + 4 FMAs/lane. Fallback to inline recompute for deg > DCAP.
__global__ __launch_bounds__(256) void k_aggregate(const _Float16* __restrict__ hh, const int* __restrict__ off,
                                                   const int* __restrict__ csrc, const float* __restrict__ avs,
                                                   const float* __restrict__ avd, const float* __restrict__ bias,
                                                   _Float16* __restrict__ outh, int n) {
    __shared__ float ew[4][DCAP];
    int wv = threadIdx.x >> 6;
    int w = (blockIdx.x * 256 + threadIdx.x) >> 6;
    int lane = threadIdx.x & 63;
    if (w >= n) return;
    int half = lane >> 5;
    int sl = lane & 31;
    int beg = off[w], end = off[w + 1];
    int deg = end - beg;
    float adn = avd[w];
    float4 acc = make_float4(0.f, 0.f, 0.f, 0.f);
    float ssum = 0.f;

    if (deg <= DCAP) {
        // pass 1a: scores to LDS + max
        float m = -1e30f;
        for (int j = beg + lane; j < end; j += 64) {
            float sc = avs[csrc[j]] + adn;
            sc = (sc < 0.f) ? 0.2f * sc : sc;
            ew[wv][j - beg] = sc;
            m = fmaxf(m, sc);
        }
        #pragma unroll
        for (int d = 32; d > 0; d >>= 1) m = fmaxf(m, __shfl_xor(m, d));
        // pass 1b: exp to LDS + sum
        float ss = 0.f;
        for (int j = beg + lane; j < end; j += 64) {
            float e = __expf(ew[wv][j - beg] - m);
            ew[wv][j - beg] = e;
            ss += e;
        }
        #pragma unroll
        for (int d = 32; d > 0; d >>= 1) ss += __shfl_xor(ss, d);
        ssum = ss;
        // pass 2: half-wave per edge, weights from LDS (broadcast)
        int j = beg + half;
        for (; j + 6 < end; j += 8) {
            int s0 = csrc[j], s1 = csrc[j + 2], s2 = csrc[j + 4], s3 = csrc[j + 6];
            h4 h0 = ((const h4*)(hh + (size_t)s0 * 128))[sl];
            h4 h1 = ((const h4*)(hh + (size_t)s1 * 128))[sl];
            h4 h2 = ((const h4*)(hh + (size_t)s2 * 128))[sl];
            h4 h3 = ((const h4*)(hh + (size_t)s3 * 128))[sl];
            float e0 = ew[wv][j - beg],     e1 = ew[wv][j + 2 - beg];
            float e2 = ew[wv][j + 4 - beg], e3 = ew[wv][j + 6 - beg];
            acc.x += e0 * (float)h0.x + e1 * (float)h1.x + e2 * (float)h2.x + e3 * (float)h3.x;
            acc.y += e0 * (float)h0.y + e1 * (float)h1.y + e2 * (float)h2.y + e3 * (float)h3.y;
            acc.z += e0 * (float)h0.z + e1 * (float)h1.z + e2 * (float)h2.z + e3 * (float)h3.z;
            acc.w += e0 * (float)h0.w + e1 * (float)h1.w + e2 * (float)h2.w + e3 * (float)h3.w;
        }
        for (; j < end; j += 2) {
            int s0 = csrc[j];
            h4 h0 = ((const h4*)(hh + (size_t)s0 * 128))[sl];
            float e0 = ew[wv][j - beg];
            acc.x += e0 * (float)h0.x;
            acc.y += e0 * (float)h0.y;
            acc.z += e0 * (float)h0.z;
            acc.w += e0 * (float)h0.w;
        }
        acc.x += __shfl_xor(acc.x, 32);
        acc.y += __shfl_xor(acc.y, 32);
        acc.z += __shfl_xor(acc.z, 32);
        acc.w += __shfl_xor(acc.w, 32);
    } else {
        // fallback: inline score recompute (R8 path)
        float m = -1e30f;
        for (int j = beg + lane; j < end; j += 64) {
            float sc = avs[csrc[j]] + adn;
            sc = (sc < 0.f) ? 0.2f * sc : sc;
            m = fmaxf(m, sc);
        }
        #pragma unroll
        for (int d = 32; d > 0; d >>= 1) m = fmaxf(m, __shfl_xor(m, d));
        float ss = 0.f;
        for (int j = beg + half; j < end; j += 2) {
            int s0 = csrc[j];
            h4 h0 = ((const h4*)(hh + (size_t)s0 * 128))[sl];
            float sc0 = avs[s0] + adn; sc0 = (sc0 < 0.f) ? 0.2f * sc0 : sc0;
            float e0 = __expf(sc0 - m);
            ss += e0;
            acc.x += e0 * (float)h0.x;
            acc.y += e0 * (float)h0.y;
            acc.z += e0 * (float)h0.z;
            acc.w += e0 * (float)h0.w;
        }
        ss    += __shfl_xor(ss, 32);
        acc.x += __shfl_xor(acc.x, 32);
        acc.y += __shfl_xor(acc.y, 32);
        acc.z += __shfl_xor(acc.z, 32);
        acc.w += __shfl_xor(acc.w, 32);
        ssum = ss;
    }
    if (half == 0) {
        float inv = 1.f / ssum;
        float4 b = ((const float4*)bias)[sl];
        h4 o;
        o.x = (_Float16)fmaxf(acc.x * inv + b.x, 0.f);
        o.y = (_Float16)fmaxf(acc.y * inv + b.y, 0.f);
        o.z = (_Float16)fmaxf(acc.z * inv + b.z, 0.f);
        o.w = (_Float16)fmaxf(acc.w * inv + b.w, 0.f);
        *((h4*)(outh + (size_t)w * 128) + sl) = o;
    }
}

// out[n,c] = mid[n,:256] @ Wm2[:,c] + bm2[c]; one wave per node, Wm2 in LDS
__global__ __launch_bounds__(256) void k_mlp2(const float* __restrict__ mid, const float* __restrict__ W2,
                                              const float* __restrict__ b2, float* __restrict__ out, int n) {
    __shared__ float Ws[256 * 6];
    int tid = threadIdx.x;
    for (int t = tid; t < 256 * 6; t += 256) Ws[t] = W2[t];
    __syncthreads();
    int w = (blockIdx.x * 256 + tid) >> 6;
    int lane = tid & 63;
    if (w >= n) return;
    float acc[6];
    float4 mv = ((const float4*)(mid + (size_t)w * 256))[lane];
    int k0 = lane * 4;
    #pragma unroll
    for (int c = 0; c < 6; ++c)
        acc[c] = mv.x * Ws[k0 * 6 + c] + mv.y * Ws[(k0 + 1) * 6 + c]
               + mv.z * Ws[(k0 + 2) * 6 + c] + mv.w * Ws[(k0 + 3) * 6 + c];
    #pragma unroll
    for (int c = 0; c < 6; ++c)
        #pragma unroll
        for (int d = 32; d > 0; d >>= 1) acc[c] += __shfl_down(acc[c], d);
    if (lane == 0) {
        #pragma unroll
        for (int c = 0; c < 6; ++c) out[(size_t)w * 6 + c] = acc[c] + b2[c];
    }
}

extern "C" void kernel_launch(void* const* d_in, const int* in_sizes, int n_in,
                              void* d_out, int out_size, void* d_ws, size_t ws_size,
                              hipStream_t stream) {
    const float* x   = (const float*)d_in[0];
    const int*   ei  = (const int*)d_in[1];
    const float* W[3]    = {(const float*)d_in[2], (const float*)d_in[6], (const float*)d_in[10]};
    const float* bL[3]   = {(const float*)d_in[3], (const float*)d_in[7], (const float*)d_in[11]};
    const float* asr[3]  = {(const float*)d_in[4], (const float*)d_in[8], (const float*)d_in[12]};
    const float* ads[3]  = {(const float*)d_in[5], (const float*)d_in[9], (const float*)d_in[13]};
    const float* Wm1 = (const float*)d_in[14];
    const float* bm1 = (const float*)d_in[15];
    const float* Wm2 = (const float*)d_in[16];
    const float* bm2 = (const float*)d_in[17];
    float* out = (float*)d_out;

    const int N_ = in_sizes[0] / 128;
    const int E_ = in_sizes[1] / 2;
    const int TOT = E_ + N_;
    const int NB = (N_ + 255) / 256;

    char* p = (char*)d_ws;
    auto alloc = [&](size_t bytes) { void* r = (void*)p; p += (bytes + 255) & ~(size_t)255; return r; };
    size_t npad = ((size_t)N_ * 4 + 255) & ~(size_t)255;
    int*   deg  = (int*)alloc(npad);
    int*   off  = (int*)alloc((size_t)(N_ + 1) * 4);
    int*   bsum = (int*)alloc((size_t)(NB + 1) * 4);
    int*   rank = (int*)alloc((size_t)TOT * 4);
    int*   csrc = (int*)alloc((size_t)TOT * 4);
    float* avs  = (float*)alloc((size_t)N_ * 4);
    float* avd  = (float*)alloc((size_t)N_ * 4);
    _Float16* Wt3  = (_Float16*)alloc(3 * 16384 * 2);
    _Float16* Wm1t = (_Float16*)alloc(32768 * 2);
    _Float16* xh   = (_Float16*)alloc((size_t)N_ * 128 * 2);
    _Float16* agg  = (_Float16*)alloc((size_t)N_ * 128 * 2);
    float*    mid  = (float*)alloc((size_t)N_ * 256 * 4);
    _Float16* hh   = (_Float16*)mid;   // layers' hh aliases MLP's mid (disjoint in time)

    // ---- CSR build + precision prep ----
    hipMemsetAsync(deg, 0, npad, stream);
    k_hist<<<(TOT + 255) / 256, 256, 0, stream>>>(ei, deg, rank, E_, N_);
    k_bsum<<<NB, 256, 0, stream>>>(deg, bsum, N_);
    k_scanb<<<1, 256, 0, stream>>>(bsum, NB);
    k_off<<<NB, 256, 0, stream>>>(deg, bsum, off, N_);
    k_scatter<<<(TOT + 255) / 256, 256, 0, stream>>>(ei, off, rank, csrc, E_, N_);
    k_cvt<<<(N_ * 32 + 255) / 256, 256, 0, stream>>>(x, xh, N_ * 32);
    k_wt3<<<192, 256, 0, stream>>>(W[0], W[1], W[2], Wt3);
    k_wt1<<<128, 256, 0, stream>>>(Wm1, Wm1t);

    const int wave_blocks = (N_ + 3) / 4;
    const int gat_blocks = (N_ + 63) / 64;

    // ---- 3 GAT layers ----
    const _Float16* cur_in = xh;
    for (int l = 0; l < 3; ++l) {
        k_mfma_gat<<<gat_blocks, 256, 0, stream>>>(cur_in, Wt3 + l * 16384, asr[l], ads[l],
                                                   hh, avs, avd, N_);
        k_aggregate<<<wave_blocks, 256, 0, stream>>>(hh, off, csrc, avs, avd, bL[l], agg, N_);
        cur_in = agg;
    }

    // ---- MLP head ----
    dim3 gm1(2, gat_blocks);
    k_mfma_mlp<<<gm1, 256, 0, stream>>>(agg, Wm1t, bm1, mid, N_);
    k_mlp2<<<wave_blocks, 256, 0, stream>>>(mid, Wm2, bm2, out, N_);
}

// Round 10
// 364.881 us; speedup vs baseline: 2.0938x; 1.0357x over previous
//
#include <hip/hip_runtime.h>
#include <hip/hip_bf16.h>

// GAT (3 layers) + MLP head. N=50000, E=800000 (+N self loops), D=128, H=256, C=6.
// Round 10: (1) 256->6 projection fused into MLP MFMA epilogue (atomicAdd, out
// pre-zeroed) — kills k_mlp2 + the 51.2MB fp32 mid round-trip. (2) aggregate
// pass-2 in 16-lane groups with half8 (b128) gathers — 4x fewer load instrs,
// same bytes, more MLP per wave. (3) prep (cvt+wt3+wt1) merged into one kernel.

typedef _Float16 h4 __attribute__((ext_vector_type(4)));
typedef _Float16 half8 __attribute__((ext_vector_type(8)));
typedef float f32x4 __attribute__((ext_vector_type(4)));

#define LDA 136   // padded fp16 row stride for MFMA staging
#define DCAP 256  // max degree handled by the LDS fast path

__global__ __launch_bounds__(256) void k_hist(const int* __restrict__ ei, int* __restrict__ deg,
                                              int* __restrict__ rank, int E_, int N_) {
    int e = blockIdx.x * 256 + threadIdx.x;
    int total = E_ + N_;
    if (e >= total) return;
    int d = (e < E_) ? ei[E_ + e] : (e - E_);
    rank[e] = atomicAdd(&deg[d], 1);
}

__device__ inline int block_incl_scan(int v, int* wsum) {
    int lane = threadIdx.x & 63, wid = threadIdx.x >> 6;
    #pragma unroll
    for (int d = 1; d < 64; d <<= 1) {
        int t = __shfl_up(v, d);
        if (lane >= d) v += t;
    }
    if (lane == 63) wsum[wid] = v;
    __syncthreads();
    if (wid == 0 && lane < 4) {
        int s = wsum[lane];
        #pragma unroll
        for (int d = 1; d < 4; d <<= 1) {
            int t = __shfl_up(s, d);
            if (lane >= d) s += t;
        }
        wsum[lane] = s;
    }
    __syncthreads();
    if (wid > 0) v += wsum[wid - 1];
    return v;
}

__global__ __launch_bounds__(256) void k_bsum(const int* __restrict__ deg, int* __restrict__ bsum, int n) {
    __shared__ int wsum[4];
    int i = blockIdx.x * 256 + threadIdx.x;
    int v = (i < n) ? deg[i] : 0;
    int lane = threadIdx.x & 63, wid = threadIdx.x >> 6;
    #pragma unroll
    for (int d = 32; d > 0; d >>= 1) v += __shfl_down(v, d);
    if (lane == 0) wsum[wid] = v;
    __syncthreads();
    if (threadIdx.x == 0) bsum[blockIdx.x] = wsum[0] + wsum[1] + wsum[2] + wsum[3];
}

__global__ __launch_bounds__(256) void k_scanb(int* __restrict__ bsum, int nb) {
    __shared__ int wsum[4];
    int i = threadIdx.x;
    int orig = (i < nb) ? bsum[i] : 0;
    int v = block_incl_scan(orig, wsum);
    if (i < nb) bsum[i] = v - orig;
}

__global__ __launch_bounds__(256) void k_off(const int* __restrict__ deg, const int* __restrict__ bsum,
                                             int* __restrict__ off, int n) {
    __shared__ int wsum[4];
    int i = blockIdx.x * 256 + threadIdx.x;
    int orig = (i < n) ? deg[i] : 0;
    int v = block_incl_scan(orig, wsum);
    int base = bsum[blockIdx.x];
    if (i < n) off[i] = base + v - orig;
    if (i == n - 1) off[n] = base + v;
}

__global__ __launch_bounds__(256) void k_scatter(const int* __restrict__ ei, const int* __restrict__ off,
                                                 const int* __restrict__ rank, int* __restrict__ csrc,
                                                 int E_, int N_) {
    int e = blockIdx.x * 256 + threadIdx.x;
    int total = E_ + N_;
    if (e >= total) return;
    int s, d;
    if (e < E_) { s = ei[e]; d = ei[E_ + e]; }
    else        { s = e - E_; d = e - E_; }
    csrc[off[d] + rank[e]] = s;
}

// fused prep: x->fp16, W0..W2 transpose->fp16, Wm1 transpose->fp16
__global__ __launch_bounds__(256) void k_prep(const float* __restrict__ x, _Float16* __restrict__ xh,
        const float* __restrict__ W0, const float* __restrict__ W1, const float* __restrict__ W2,
        _Float16* __restrict__ Wt3, const float* __restrict__ Wm1, _Float16* __restrict__ Wm1t, int n4) {
    int i = blockIdx.x * 256 + threadIdx.x;
    if (i < n4) {
        float4 v = ((const float4*)x)[i];
        h4 o;
        o.x = (_Float16)v.x; o.y = (_Float16)v.y; o.z = (_Float16)v.z; o.w = (_Float16)v.w;
        ((h4*)xh)[i] = o;
        return;
    }
    int t = i - n4;
    if (t < 3 * 16384) {
        int seg = t >> 14;
        int j = t & 16383;
        const float* W = (seg == 0) ? W0 : (seg == 1) ? W1 : W2;
        int nn = j >> 7, k = j & 127;
        Wt3[t] = (_Float16)W[k * 128 + nn];
        return;
    }
    t -= 3 * 16384;
    if (t < 32768) {
        int nn = t >> 7, k = t & 127;
        Wm1t[t] = (_Float16)Wm1[k * 256 + nn];
    }
}

// Layer GEMM via MFMA: hh[M x 128](fp16) = A16[M x 128] @ W + fused alpha dots.
__global__ __launch_bounds__(256, 3) void k_mfma_gat(const _Float16* __restrict__ A16,
        const _Float16* __restrict__ Wt, const float* __restrict__ asrc, const float* __restrict__ adst,
        _Float16* __restrict__ hh, float* __restrict__ avs, float* __restrict__ avd, int M) {
    __shared__ _Float16 As[64 * LDA];
    __shared__ _Float16 Bs[128 * LDA];
    int tid = threadIdx.x;
    int bm = blockIdx.x * 64;
    #pragma unroll
    for (int i = 0; i < 4; ++i) {
        int idx = i * 256 + tid;
        int row = idx >> 4, c16 = idx & 15;
        int gr = bm + row;
        uint4 v = make_uint4(0u, 0u, 0u, 0u);
        if (gr < M) v = *(const uint4*)(A16 + (size_t)gr * 128 + c16 * 8);
        *(uint4*)&As[row * LDA + c16 * 8] = v;
    }
    #pragma unroll
    for (int i = 0; i < 8; ++i) {
        int idx = i * 256 + tid;
        int row = idx >> 4, c16 = idx & 15;
        *(uint4*)&Bs[row * LDA + c16 * 8] = *(const uint4*)(Wt + (size_t)row * 128 + c16 * 8);
    }
    __syncthreads();
    int w = tid >> 6, l = tid & 63;
    int quad = l >> 4, cl = l & 15;
    f32x4 acc[8] = {};
    const _Float16* ap = &As[(w * 16 + cl) * LDA + quad * 8];
    #pragma unroll
    for (int kt = 0; kt < 4; ++kt) {
        half8 a = *(const half8*)(ap + kt * 32);
        #pragma unroll
        for (int ct = 0; ct < 8; ++ct) {
            half8 b = *(const half8*)&Bs[(ct * 16 + cl) * LDA + kt * 32 + quad * 8];
            acc[ct] = __builtin_amdgcn_mfma_f32_16x16x32_f16(a, b, acc[ct], 0, 0, 0);
        }
    }
    float sa[8], da[8];
    #pragma unroll
    for (int ct = 0; ct < 8; ++ct) { sa[ct] = asrc[ct * 16 + cl]; da[ct] = adst[ct * 16 + cl]; }
    #pragma unroll
    for (int r = 0; r < 4; ++r) {
        int row = bm + w * 16 + quad * 4 + r;
        bool ok = row < M;
        float ps = 0.f, pd = 0.f;
        #pragma unroll
        for (int ct = 0; ct < 8; ++ct) {
            float v = acc[ct][r];
            if (ok) hh[(size_t)row * 128 + ct * 16 + cl] = (_Float16)v;
            ps += v * sa[ct];
            pd += v * da[ct];
        }
        #pragma unroll
        for (int msk = 1; msk <= 8; msk <<= 1) { ps += __shfl_xor(ps, msk); pd += __shfl_xor(pd, msk); }
        if (cl == 0 && ok) { avs[row] = ps; avd[row] = pd; }
    }
}

// Fused MLP: out[M x 6] += relu(A16 @ Wm1 + bm1)[:, bn:bn+128] @ Wm2[bn:bn+128, :]
// grid (2, M/64); out pre-zeroed; bm2 added by bn==0 block only.
__global__ __launch_bounds__(256, 3) void k_mfma_mlp(const _Float16* __restrict__ A16,
        const _Float16* __restrict__ Wt, const float* __restrict__ bias,
        const float* __restrict__ W2, const float* __restrict__ b2,
        float* __restrict__ out, int M) {
    __shared__ _Float16 As[64 * LDA];
    __shared__ _Float16 Bs[128 * LDA];
    int tid = threadIdx.x;
    int bm = blockIdx.y * 64;
    int bn = blockIdx.x * 128;
    #pragma unroll
    for (int i = 0; i < 4; ++i) {
        int idx = i * 256 + tid;
        int row = idx >> 4, c16 = idx & 15;
        int gr = bm + row;
        uint4 v = make_uint4(0u, 0u, 0u, 0u);
        if (gr < M) v = *(const uint4*)(A16 + (size_t)gr * 128 + c16 * 8);
        *(uint4*)&As[row * LDA + c16 * 8] = v;
    }
    #pragma unroll
    for (int i = 0; i < 8; ++i) {
        int idx = i * 256 + tid;
        int row = idx >> 4, c16 = idx & 15;
        *(uint4*)&Bs[row * LDA + c16 * 8] = *(const uint4*)(Wt + (size_t)(bn + row) * 128 + c16 * 8);
    }
    __syncthreads();
    int w = tid >> 6, l = tid & 63;
    int quad = l >> 4, cl = l & 15;
    f32x4 acc[8] = {};
    const _Float16* ap = &As[(w * 16 + cl) * LDA + quad * 8];
    #pragma unroll
    for (int kt = 0; kt < 4; ++kt) {
        half8 a = *(const half8*)(ap + kt * 32);
        #pragma unroll
        for (int ct = 0; ct < 8; ++ct) {
            half8 b = *(const half8*)&Bs[(ct * 16 + cl) * LDA + kt * 32 + quad * 8];
            acc[ct] = __builtin_amdgcn_mfma_f32_16x16x32_f16(a, b, acc[ct], 0, 0, 0);
        }
    }
    float bs[8];
    float w2r[8][6];
    #pragma unroll
    for (int ct = 0; ct < 8; ++ct) {
        int hcol = bn + ct * 16 + cl;
        bs[ct] = bias[hcol];
        #pragma unroll
        for (int c = 0; c < 6; ++c) w2r[ct][c] = W2[hcol * 6 + c];
    }
    #pragma unroll
    for (int r = 0; r < 4; ++r) {
        int row = bm + w * 16 + quad * 4 + r;
        if (row >= M) continue;
        float pc[6] = {};
        #pragma unroll
        for (int ct = 0; ct < 8; ++ct) {
            float v = fmaxf(acc[ct][r] + bs[ct], 0.f);
            #pragma unroll
            for (int c = 0; c < 6; ++c) pc[c] += v * w2r[ct][c];
        }
        #pragma unroll
        for (int msk = 1; msk <= 8; msk <<= 1) {
            #pragma unroll
            for (int c = 0; c < 6; ++c) pc[c] += __shfl_xor(pc[c], msk);
        }
        if (cl == 0) {
            #pragma unroll
            for (int c = 0; c < 6; ++c) {
                float add = pc[c] + (blockIdx.x == 0 ? b2[c] : 0.f);
                atomicAdd(&out[(size_t)row * 6 + c], add);
            }
        }
    }
}

// one wave per dst node. Pass 1 (64-lane edge-parallel): score->LDS, max, exp->LDS, sum.
// Pass 2: 16-lane group per edge, half8 (16B) gathers, weights from LDS broadcast.
__global__ __launch_bounds__(256) void k_aggregate(const _Float16* __restrict__ hh, const int* __restrict__ off,
                                                   const int* __restrict__ csrc, const float* __restrict__ avs,
                                                   const float* __restrict__ avd, const float* __restrict__ bias,
                                                   _Float16* __restrict__ outh, int n) {
    __shared__ float ew[4][DCAP];
    int wv = threadIdx.x >> 6;
    int w = (blockIdx.x * 256 + threadIdx.x) >> 6;
    int lane = threadIdx.x & 63;
    if (w >= n) return;
    int grp = lane >> 4;
    int gl = lane & 15;
    int beg = off[w], end = off[w + 1];
    int deg = end - beg;
    float adn = avd[w];
    float accf[8] = {};
    float ssum = 0.f;

    if (deg <= DCAP) {
        // pass 1a: scores to LDS + max
        float m = -1e30f;
        for (int j = beg + lane; j < end; j += 64) {
            float sc = avs[csrc[j]] + adn;
            sc = (sc < 0.f) ? 0.2f * sc : sc;
            ew[wv][j - beg] = sc;
            m = fmaxf(m, sc);
        }
        #pragma unroll
        for (int d = 32; d > 0; d >>= 1) m = fmaxf(m, __shfl_xor(m, d));
        // pass 1b: exp to LDS + sum
        float ss = 0.f;
        for (int j = beg + lane; j < end; j += 64) {
            float e = __expf(ew[wv][j - beg] - m);
            ew[wv][j - beg] = e;
            ss += e;
        }
        #pragma unroll
        for (int d = 32; d > 0; d >>= 1) ss += __shfl_xor(ss, d);
        ssum = ss;
        // pass 2: 16-lane group per edge (stride 4), half8 loads, 2x unroll
        int j = beg + grp;
        for (; j + 4 < end; j += 8) {
            int s0 = csrc[j], s1 = csrc[j + 4];
            half8 v0 = *((const half8*)(hh + (size_t)s0 * 128) + gl);
            half8 v1 = *((const half8*)(hh + (size_t)s1 * 128) + gl);
            float e0 = ew[wv][j - beg], e1 = ew[wv][j + 4 - beg];
            #pragma unroll
            for (int f = 0; f < 8; ++f) accf[f] += e0 * (float)v0[f] + e1 * (float)v1[f];
        }
        for (; j < end; j += 4) {
            int s0 = csrc[j];
            half8 v0 = *((const half8*)(hh + (size_t)s0 * 128) + gl);
            float e0 = ew[wv][j - beg];
            #pragma unroll
            for (int f = 0; f < 8; ++f) accf[f] += e0 * (float)v0[f];
        }
    } else {
        // fallback: inline recompute, 16-lane group per edge
        float m = -1e30f;
        for (int j = beg + lane; j < end; j += 64) {
            float sc = avs[csrc[j]] + adn;
            sc = (sc < 0.f) ? 0.2f * sc : sc;
            m = fmaxf(m, sc);
        }
        #pragma unroll
        for (int d = 32; d > 0; d >>= 1) m = fmaxf(m, __shfl_xor(m, d));
        float ss = 0.f;
        for (int j = beg + grp; j < end; j += 4) {
            int s0 = csrc[j];
            half8 v0 = *((const half8*)(hh + (size_t)s0 * 128) + gl);
            float sc = avs[s0] + adn; sc = (sc < 0.f) ? 0.2f * sc : sc;
            float e0 = __expf(sc - m);
            ss += e0;                       // identical across the 16 lanes of the group
            #pragma unroll
            for (int f = 0; f < 8; ++f) accf[f] += e0 * (float)v0[f];
        }
        ssum = ss;                          // per-group value; combined below via xor 16/32
    }
    // combine the 4 groups (one lane per group at fixed gl)
    #pragma unroll
    for (int f = 0; f < 8; ++f) {
        accf[f] += __shfl_xor(accf[f], 16);
        accf[f] += __shfl_xor(accf[f], 32);
    }
    if (deg > DCAP) {
        ssum += __shfl_xor(ssum, 16);
        ssum += __shfl_xor(ssum, 32);
    }
    if (grp == 0) {
        float inv = 1.f / ssum;
        float4 b0 = ((const float4*)bias)[gl * 2];
        float4 b1 = ((const float4*)bias)[gl * 2 + 1];
        half8 o;
        o[0] = (_Float16)fmaxf(accf[0] * inv + b0.x, 0.f);
        o[1] = (_Float16)fmaxf(accf[1] * inv + b0.y, 0.f);
        o[2] = (_Float16)fmaxf(accf[2] * inv + b0.z, 0.f);
        o[3] = (_Float16)fmaxf(accf[3] * inv + b0.w, 0.f);
        o[4] = (_Float16)fmaxf(accf[4] * inv + b1.x, 0.f);
        o[5] = (_Float16)fmaxf(accf[5] * inv + b1.y, 0.f);
        o[6] = (_Float16)fmaxf(accf[6] * inv + b1.z, 0.f);
        o[7] = (_Float16)fmaxf(accf[7] * inv + b1.w, 0.f);
        *((half8*)(outh + (size_t)w * 128) + gl) = o;
    }
}

extern "C" void kernel_launch(void* const* d_in, const int* in_sizes, int n_in,
                              void* d_out, int out_size, void* d_ws, size_t ws_size,
                              hipStream_t stream) {
    const float* x   = (const float*)d_in[0];
    const int*   ei  = (const int*)d_in[1];
    const float* W[3]    = {(const float*)d_in[2], (const float*)d_in[6], (const float*)d_in[10]};
    const float* bL[3]   = {(const float*)d_in[3], (const float*)d_in[7], (const float*)d_in[11]};
    const float* asr[3]  = {(const float*)d_in[4], (const float*)d_in[8], (const float*)d_in[12]};
    const float* ads[3]  = {(const float*)d_in[5], (const float*)d_in[9], (const float*)d_in[13]};
    const float* Wm1 = (const float*)d_in[14];
    const float* bm1 = (const float*)d_in[15];
    const float* Wm2 = (const float*)d_in[16];
    const float* bm2 = (const float*)d_in[17];
    float* out = (float*)d_out;

    const int N_ = in_sizes[0] / 128;
    const int E_ = in_sizes[1] / 2;
    const int TOT = E_ + N_;
    const int NB = (N_ + 255) / 256;

    char* p = (char*)d_ws;
    auto alloc = [&](size_t bytes) { void* r = (void*)p; p += (bytes + 255) & ~(size_t)255; return r; };
    size_t npad = ((size_t)N_ * 4 + 255) & ~(size_t)255;
    int*   deg  = (int*)alloc(npad);
    int*   off  = (int*)alloc((size_t)(N_ + 1) * 4);
    int*   bsum = (int*)alloc((size_t)(NB + 1) * 4);
    int*   rank = (int*)alloc((size_t)TOT * 4);
    int*   csrc = (int*)alloc((size_t)TOT * 4);
    float* avs  = (float*)alloc((size_t)N_ * 4);
    float* avd  = (float*)alloc((size_t)N_ * 4);
    _Float16* Wt3  = (_Float16*)alloc(3 * 16384 * 2);
    _Float16* Wm1t = (_Float16*)alloc(32768 * 2);
    _Float16* xh   = (_Float16*)alloc((size_t)N_ * 128 * 2);
    _Float16* agg  = (_Float16*)alloc((size_t)N_ * 128 * 2);
    _Float16* hh   = (_Float16*)alloc((size_t)N_ * 128 * 2);

    // ---- CSR build + prep ----
    hipMemsetAsync(deg, 0, npad, stream);
    hipMemsetAsync(out, 0, (size_t)out_size * 4, stream);
    k_hist<<<(TOT + 255) / 256, 256, 0, stream>>>(ei, deg, rank, E_, N_);
    k_bsum<<<NB, 256, 0, stream>>>(deg, bsum, N_);
    k_scanb<<<1, 256, 0, stream>>>(bsum, NB);
    k_off<<<NB, 256, 0, stream>>>(deg, bsum, off, N_);
    k_scatter<<<(TOT + 255) / 256, 256, 0, stream>>>(ei, off, rank, csrc, E_, N_);
    int n4 = N_ * 32;
    int prep_items = n4 + 3 * 16384 + 32768;
    k_prep<<<(prep_items + 255) / 256, 256, 0, stream>>>(x, xh, W[0], W[1], W[2], Wt3, Wm1, Wm1t, n4);

    const int wave_blocks = (N_ + 3) / 4;
    const int gat_blocks = (N_ + 63) / 64;

    // ---- 3 GAT layers ----
    const _Float16* cur_in = xh;
    for (int l = 0; l < 3; ++l) {
        k_mfma_gat<<<gat_blocks, 256, 0, stream>>>(cur_in, Wt3 + l * 16384, asr[l], ads[l],
                                                   hh, avs, avd, N_);
        k_aggregate<<<wave_blocks, 256, 0, stream>>>(hh, off, csrc, avs, avd, bL[l], agg, N_);
        cur_in = agg;
    }

    // ---- fused MLP head ----
    dim3 gm1(2, gat_blocks);
    k_mfma_mlp<<<gm1, 256, 0, stream>>>(agg, Wm1t, bm1, Wm2, bm2, out, N_);
}